// Round 10
// baseline (408.798 us; speedup 1.0000x reference)
//
#include <hip/hip_runtime.h>
#include <hip/hip_fp16.h>
#include <hip/hip_cooperative_groups.h>

namespace cg = cooperative_groups;

#define NPIX 16384
#define NBMAX 1024

typedef __attribute__((ext_vector_type(8))) short short8;
typedef __attribute__((ext_vector_type(8))) _Float16 half8;
typedef __attribute__((ext_vector_type(4))) float f32x4;

__device__ __forceinline__ unsigned short f2bf(float f) {
    unsigned u = __float_as_uint(f);
    unsigned r = (u + 0x7fffu + ((u >> 16) & 1u)) >> 16;
    return (unsigned short)r;
}
__device__ __forceinline__ unsigned short f2h_us(float f) {
    union { _Float16 h; unsigned short u; } cv;
    cv.h = (_Float16)f;
    return cv.u;
}
__device__ __forceinline__ unsigned hdup(float f) {
    unsigned short u = f2h_us(f);
    return (unsigned)u | ((unsigned)u << 16);
}
__device__ __forceinline__ unsigned hfma2u(unsigned w, unsigned v, unsigned a) {
    union { unsigned u; __half2 h; } W, V, A, R;
    W.u = w; V.u = v; A.u = a;
    R.h = __hfma2(W.h, V.h, A.h);
    return R.u;
}
__device__ __forceinline__ unsigned hadd2u(unsigned a, unsigned b) {
    union { unsigned u; __half2 h; } A, B, R;
    A.u = a; B.u = b;
    R.h = __hadd2(A.h, B.h);
    return R.u;
}

#define GLOAD16(SRC, DST) \
    __builtin_amdgcn_global_load_lds( \
        (const __attribute__((address_space(1))) unsigned*)(SRC), \
        (__attribute__((address_space(3))) unsigned*)(DST), 16, 0, 0)

// 32 KB LDS union -> 5 blocks/CU LDS-wise; VGPR<=128 via launch_bounds -> 4.
union SMem {
    struct { float t[64][65]; } prep;                        // 16640 B
    struct { unsigned short As[64 * 128], Bs[64 * 128]; } g; // 32768 B
    struct { int offs[576 * 2]; unsigned wpk[576 * 4]; } s;  // 13824 B
};

__device__ __forceinline__ float wsrc(int k, int n,
    const float* v_w, const float* qd_w, const float* qs_w,
    const float* qw_w, const float* out_w)
{
    if (n < 256) return v_w[k * 256 + n];
    n -= 256;
    if (n < 144) return qd_w[k * 144 + n];
    n -= 144;
    if (n < 72)  return qs_w[k * 72 + n];
    n -= 72;
    if (n < 72)  return qw_w[k * 72 + n];
    n -= 72;
    if (n < 32)  return 0.f;
    return out_w[k * 256 + (n - 32)];
}

// 64x64 tile, K=256 in two K=128 halves through 32 KB LDS. Rows of 128
// elems (256 B = 16 granules of 16 B), granule XOR-swizzled by (row&7).
template<bool F16>
__device__ __forceinline__ void gemm_tile(
    const unsigned short* __restrict__ Ab,   // [64][256] at row base
    const unsigned short* __restrict__ Bb,   // [64][256] at col base
    SMem* sm, int tid, f32x4* acc)
{
    const int wid  = tid >> 6;
    const int lane = tid & 63;
    const int wr = (wid >> 1) * 32;
    const int wc = (wid & 1) * 32;
    const int fr = lane & 15;
    const int fg = lane >> 4;
    const int ra0 = wr + fr, ra1 = ra0 + 16;
    const int rb0 = wc + fr, rb1 = rb0 + 16;
    const int sa  = ra0 & 7;
    const int sb  = rb0 & 7;

    #pragma unroll
    for (int kh = 0; kh < 2; ++kh) {
        __syncthreads();   // prior reads of LDS done
        #pragma unroll
        for (int it = 0; it < 4; ++it) {
            const int rr  = it * 16 + wid * 4 + (lane >> 4);
            const int gl  = lane & 15;
            const int gsw = gl ^ (rr & 7);
            GLOAD16(Ab + rr * 256 + kh * 128 + gsw * 8, &sm->g.As[(it * 16 + wid * 4) * 128]);
            GLOAD16(Bb + rr * 256 + kh * 128 + gsw * 8, &sm->g.Bs[(it * 16 + wid * 4) * 128]);
        }
        asm volatile("s_waitcnt vmcnt(0)" ::: "memory");
        __syncthreads();

        #pragma unroll
        for (int t = 0; t < 4; ++t) {
            const int gran = t * 4 + fg;
            if (F16) {
                half8 a0 = *(const half8*)&sm->g.As[ra0 * 128 + ((gran ^ sa) * 8)];
                half8 a1 = *(const half8*)&sm->g.As[ra1 * 128 + ((gran ^ sa) * 8)];
                half8 b0 = *(const half8*)&sm->g.Bs[rb0 * 128 + ((gran ^ sb) * 8)];
                half8 b1 = *(const half8*)&sm->g.Bs[rb1 * 128 + ((gran ^ sb) * 8)];
                acc[0] = __builtin_amdgcn_mfma_f32_16x16x32_f16(a0, b0, acc[0], 0, 0, 0);
                acc[1] = __builtin_amdgcn_mfma_f32_16x16x32_f16(a0, b1, acc[1], 0, 0, 0);
                acc[2] = __builtin_amdgcn_mfma_f32_16x16x32_f16(a1, b0, acc[2], 0, 0, 0);
                acc[3] = __builtin_amdgcn_mfma_f32_16x16x32_f16(a1, b1, acc[3], 0, 0, 0);
            } else {
                short8 a0 = *(const short8*)&sm->g.As[ra0 * 128 + ((gran ^ sa) * 8)];
                short8 a1 = *(const short8*)&sm->g.As[ra1 * 128 + ((gran ^ sa) * 8)];
                short8 b0 = *(const short8*)&sm->g.Bs[rb0 * 128 + ((gran ^ sb) * 8)];
                short8 b1 = *(const short8*)&sm->g.Bs[rb1 * 128 + ((gran ^ sb) * 8)];
                acc[0] = __builtin_amdgcn_mfma_f32_16x16x32_bf16(a0, b0, acc[0], 0, 0, 0);
                acc[1] = __builtin_amdgcn_mfma_f32_16x16x32_bf16(a0, b1, acc[1], 0, 0, 0);
                acc[2] = __builtin_amdgcn_mfma_f32_16x16x32_bf16(a1, b0, acc[2], 0, 0, 0);
                acc[3] = __builtin_amdgcn_mfma_f32_16x16x32_bf16(a1, b1, acc[3], 0, 0, 0);
            }
        }
    }
}

__global__ __launch_bounds__(256, 4) void mega(
    const float* __restrict__ x,
    const float* __restrict__ v_w, const float* __restrict__ v_b,
    const float* __restrict__ qd_w, const float* __restrict__ qd_b,
    const float* __restrict__ qs_w,
    const float* __restrict__ qw_w, const float* __restrict__ qw_b,
    const float* __restrict__ out_w, const float* __restrict__ out_b,
    const float* __restrict__ prior, const float* __restrict__ dscale,
    float* __restrict__ out,
    unsigned short* __restrict__ xb, unsigned short* __restrict__ v_bf,
    unsigned short* __restrict__ vpad, float* __restrict__ proj,
    unsigned short* __restrict__ mid, unsigned short* __restrict__ Wt,
    float* __restrict__ biasD)
{
    __shared__ SMem sm;
    cg::grid_group grid = cg::this_grid();
    const int tid = threadIdx.x;
    const int bid = blockIdx.x;
    const int nb  = gridDim.x;
    const int wid  = tid >> 6;
    const int lane = tid & 63;

    // ================= Stage P: x->bf16, Wt transpose, bias/pad ==========
    for (int chunk = bid; chunk < 2048; chunk += nb) {
        const size_t i = (size_t)chunk * 256 + tid;
        const float4 v0 = *(const float4*)(x + i * 8);
        const float4 v1 = *(const float4*)(x + i * 8 + 4);
        uint4 pk;
        pk.x = f2bf(v0.x) | ((unsigned)f2bf(v0.y) << 16);
        pk.y = f2bf(v0.z) | ((unsigned)f2bf(v0.w) << 16);
        pk.z = f2bf(v1.x) | ((unsigned)f2bf(v1.y) << 16);
        pk.w = f2bf(v1.z) | ((unsigned)f2bf(v1.w) << 16);
        *(uint4*)(xb + i * 8) = pk;
    }
    if (bid < 52) {
        const int tn = bid % 13;
        const int tk = bid / 13;
        #pragma unroll
        for (int i = 0; i < 16; ++i) {
            const int idx = tid + i * 256;
            const int r = idx >> 6;
            const int c = idx & 63;
            sm.prep.t[r][c] = wsrc(tk * 64 + r, tn * 64 + c, v_w, qd_w, qs_w, qw_w, out_w);
        }
        __syncthreads();
        const bool asF16 = (tn >= 9);
        #pragma unroll
        for (int i = 0; i < 8; ++i) {
            const int idx = tid + i * 256;
            const int rn = idx >> 5;
            const int cc = idx & 31;
            unsigned pk;
            if (asF16)
                pk = (unsigned)f2h_us(sm.prep.t[cc * 2][rn]) | ((unsigned)f2h_us(sm.prep.t[cc * 2 + 1][rn]) << 16);
            else
                pk = (unsigned)f2bf(sm.prep.t[cc * 2][rn]) | ((unsigned)f2bf(sm.prep.t[cc * 2 + 1][rn]) << 16);
            ((unsigned*)(Wt + (size_t)(tn * 64 + rn) * 256 + tk * 64))[cc] = pk;
        }
    }
    if (bid == 52) {
        for (int i = tid; i < 320; i += 256) {
            float bv = 0.f;
            if (i < 144)                  bv = qd_b[i];
            else if (i >= 216 && i < 288) bv = qw_b[i - 216];
            biasD[i] = bv;
        }
        for (int i = tid; i < 512; i += 256) vpad[i] = 0;
    }
    __threadfence();
    grid.sync();

    // ================= Stage G1: projection GEMM (2304 jobs) =============
    for (int job = bid; job < 2304; job += nb) {
        const int rt = job & 255;
        const int j  = job >> 8;
        const int row0 = rt * 64;

        f32x4 acc[4] = {{0,0,0,0},{0,0,0,0},{0,0,0,0},{0,0,0,0}};
        gemm_tile<false>(xb + (size_t)row0 * 256, Wt + (size_t)(j * 64) * 256,
                         &sm, tid, acc);

        const int wr = (wid >> 1) * 32;
        const int wc = (wid & 1) * 32;
        const int fr = lane & 15;
        const int fg = lane >> 4;
        if (j < 4) {
            const int colA = j * 64 + wc + fr;
            const int colB = colA + 16;
            const int gA = colA >> 5, cA = colA & 31;
            const int gB = colB >> 5, cB = colB & 31;
            const float biasA = v_b[colA];
            const float biasB = v_b[colB];
            #pragma unroll
            for (int jj = 0; jj < 4; ++jj) {
                const int r0a = row0 + wr + fg * 4 + jj;
                const int r1a = r0a + 16;
                const int b0i = r0a >> 12;
                const int hw0 = r0a & 4095, hw1 = r1a & 4095;
                v_bf[((size_t)(b0i * 8 + gA) * 4096 + hw0) * 32 + cA] = f2h_us(acc[0][jj] + biasA);
                v_bf[((size_t)(b0i * 8 + gB) * 4096 + hw0) * 32 + cB] = f2h_us(acc[1][jj] + biasB);
                v_bf[((size_t)(b0i * 8 + gA) * 4096 + hw1) * 32 + cA] = f2h_us(acc[2][jj] + biasA);
                v_bf[((size_t)(b0i * 8 + gB) * 4096 + hw1) * 32 + cB] = f2h_us(acc[3][jj] + biasB);
            }
        } else {
            const int colA = (j - 4) * 64 + wc + fr;
            const int colB = colA + 16;
            const float biasA = biasD[colA];
            const float biasB = biasD[colB];
            #pragma unroll
            for (int jj = 0; jj < 4; ++jj) {
                const int r0a = row0 + wr + fg * 4 + jj;
                const int r1a = r0a + 16;
                proj[(size_t)r0a * 320 + colA] = acc[0][jj] + biasA;
                proj[(size_t)r0a * 320 + colB] = acc[1][jj] + biasB;
                proj[(size_t)r1a * 320 + colA] = acc[2][jj] + biasA;
                proj[(size_t)r1a * 320 + colB] = acc[3][jj] + biasB;
            }
        }
    }
    __threadfence();
    grid.sync();

    // ================= Stage S: deformable sampling (2048 octets) ========
    for (int oct = bid; oct < 2048; oct += nb) {
        const int pix0 = oct * 8;
        __syncthreads();   // LDS reuse across octets / stages

        for (int it = tid; it < 576; it += 256) {
            const int p   = it / 72;
            const int rem = it - p * 72;
            const int g   = rem / 9;
            const int k   = rem - g * 9;
            const int pix = pix0 + p;
            const int b   = pix >> 12;
            const int hw  = pix & 4095;
            const int h   = hw >> 6, w = hw & 63;

            const float* row = proj + (size_t)pix * 320;
            const float qdx = row[g * 18 + k * 2 + 0];
            const float qdy = row[g * 18 + k * 2 + 1];
            const float s   = row[144 + g * 9 + k] + dscale[g];
            const float wt  = row[216 + g * 9 + k];
            const float sig6 = 6.0f / (1.0f + __expf(-s));
            const float px = (float)w + (qdx + prior[k * 2 + 0]) * sig6;
            const float py = (float)h + (qdy + prior[k * 2 + 1]) * sig6;

            const float x0f = floorf(px), y0f = floorf(py);
            const int ix = (int)x0f, iy = (int)y0f;
            const float wx1 = px - x0f, wx0 = 1.f - wx1;
            const float wy1 = py - y0f, wy0 = 1.f - wy1;
            const int plane = (b * 8 + g) << 12;

            const bool vy0 = (iy >= 0) & (iy < 64);
            const bool vy1 = (iy >= -1) & (iy < 63);
            const bool vx0 = (ix >= 0) & (ix < 64);
            const bool vx1 = (ix >= -1) & (ix < 63);
            const float w00 = (vy0 & vx0) ? wt * wy0 * wx0 : 0.f;
            const float w10 = (vy1 & vx0) ? wt * wy1 * wx0 : 0.f;
            const float w01 = (vy0 & vx1) ? wt * wy0 * wx1 : 0.f;
            const float w11 = (vy1 & vx1) ? wt * wy1 * wx1 : 0.f;
            sm.s.wpk[it * 4 + 0] = hdup(w00);
            sm.s.wpk[it * 4 + 1] = hdup(w10);
            sm.s.wpk[it * 4 + 2] = hdup(w01);
            sm.s.wpk[it * 4 + 3] = hdup(w11);

            const int xs  = min(max(ix,     -1), 63);
            const int y0c = min(max(iy,      0), 63);
            const int y1c = min(max(iy + 1,  0), 63);
            sm.s.offs[it * 2 + 0] = (plane + y0c * 64 + xs) * 64;   // bytes
            sm.s.offs[it * 2 + 1] = (plane + y1c * 64 + xs) * 64;
        }
        __syncthreads();

        const int p4 = tid >> 6;
        const int g  = (tid >> 3) & 7;
        const int q  = tid & 7;
        const int xh = q >> 2;
        const int qb = q * 16;
        const char* vbb = (const char*)v_bf;

        unsigned aA0=0,aA1=0,aA2=0,aA3=0, aB0=0,aB1=0,aB2=0,aB3=0;
        unsigned bA0=0,bA1=0,bA2=0,bA3=0, bB0=0,bB1=0,bB2=0,bB3=0;
        const int item0a = p4 * 72 + g * 9;
        const int item0b = (p4 + 4) * 72 + g * 9;

        #pragma unroll
        for (int k = 0; k < 9; ++k) {
            {
                const int it = item0a + k;
                const int2  o2 = *(const int2*)&sm.s.offs[it * 2];
                const uint2 wp = *(const uint2*)&sm.s.wpk[it * 4 + xh * 2];
                const uint4 r0 = *(const uint4*)(vbb + o2.x + qb);
                const uint4 r1 = *(const uint4*)(vbb + o2.y + qb);
                aA0 = hfma2u(wp.x, r0.x, aA0);
                aA1 = hfma2u(wp.x, r0.y, aA1);
                aA2 = hfma2u(wp.x, r0.z, aA2);
                aA3 = hfma2u(wp.x, r0.w, aA3);
                aB0 = hfma2u(wp.y, r1.x, aB0);
                aB1 = hfma2u(wp.y, r1.y, aB1);
                aB2 = hfma2u(wp.y, r1.z, aB2);
                aB3 = hfma2u(wp.y, r1.w, aB3);
            }
            {
                const int it = item0b + k;
                const int2  o2 = *(const int2*)&sm.s.offs[it * 2];
                const uint2 wp = *(const uint2*)&sm.s.wpk[it * 4 + xh * 2];
                const uint4 r0 = *(const uint4*)(vbb + o2.x + qb);
                const uint4 r1 = *(const uint4*)(vbb + o2.y + qb);
                bA0 = hfma2u(wp.x, r0.x, bA0);
                bA1 = hfma2u(wp.x, r0.y, bA1);
                bA2 = hfma2u(wp.x, r0.z, bA2);
                bA3 = hfma2u(wp.x, r0.w, bA3);
                bB0 = hfma2u(wp.y, r1.x, bB0);
                bB1 = hfma2u(wp.y, r1.y, bB1);
                bB2 = hfma2u(wp.y, r1.z, bB2);
                bB3 = hfma2u(wp.y, r1.w, bB3);
            }
        }

        uint4 oA, oB;
        {
            unsigned c;
            c = hadd2u(aA0, aB0); c = hadd2u(c, (unsigned)__shfl_xor((int)c, 4)); oA.x = c;
            c = hadd2u(aA1, aB1); c = hadd2u(c, (unsigned)__shfl_xor((int)c, 4)); oA.y = c;
            c = hadd2u(aA2, aB2); c = hadd2u(c, (unsigned)__shfl_xor((int)c, 4)); oA.z = c;
            c = hadd2u(aA3, aB3); c = hadd2u(c, (unsigned)__shfl_xor((int)c, 4)); oA.w = c;
            c = hadd2u(bA0, bB0); c = hadd2u(c, (unsigned)__shfl_xor((int)c, 4)); oB.x = c;
            c = hadd2u(bA1, bB1); c = hadd2u(c, (unsigned)__shfl_xor((int)c, 4)); oB.y = c;
            c = hadd2u(bA2, bB2); c = hadd2u(c, (unsigned)__shfl_xor((int)c, 4)); oB.z = c;
            c = hadd2u(bA3, bB3); c = hadd2u(c, (unsigned)__shfl_xor((int)c, 4)); oB.w = c;
        }
        if (xh == 0) {
            const int cq8 = (q & 3) * 8;
            *(uint4*)(mid + (size_t)(pix0 + p4) * 256 + g * 32 + cq8) = oA;
            *(uint4*)(mid + (size_t)(pix0 + p4 + 4) * 256 + g * 32 + cq8) = oB;
        }
    }
    __threadfence();
    grid.sync();

    // ================= Stage G2: output GEMM (1024 jobs) =================
    for (int job = bid; job < 1024; job += nb) {
        const int rt = job & 255;
        const int ct = job >> 8;
        const int row0 = rt * 64;
        const int col0 = ct * 64;

        f32x4 acc[4] = {{0,0,0,0},{0,0,0,0},{0,0,0,0},{0,0,0,0}};
        gemm_tile<true>(mid + (size_t)row0 * 256,
                        Wt + (size_t)(576 + col0) * 256, &sm, tid, acc);

        const int wr = (wid >> 1) * 32;
        const int wc = (wid & 1) * 32;
        const int fr = lane & 15;
        const int fg = lane >> 4;
        const int colA = col0 + wc + fr;
        const int colB = colA + 16;
        const float biasA = out_b[colA];
        const float biasB = out_b[colB];
        #pragma unroll
        for (int jj = 0; jj < 4; ++jj) {
            const int r0a = row0 + wr + fg * 4 + jj;
            const int r1a = r0a + 16;
            out[(size_t)r0a * 256 + colA] = acc[0][jj] + biasA;
            out[(size_t)r0a * 256 + colB] = acc[1][jj] + biasB;
            out[(size_t)r1a * 256 + colA] = acc[2][jj] + biasA;
            out[(size_t)r1a * 256 + colB] = acc[3][jj] + biasB;
        }
    }
}

// ---------------------------------------------------------------------------
extern "C" void kernel_launch(void* const* d_in, const int* in_sizes, int n_in,
                              void* d_out, int out_size, void* d_ws, size_t ws_size,
                              hipStream_t stream)
{
    (void)in_sizes; (void)n_in; (void)out_size; (void)ws_size;

    const float* x      = (const float*)d_in[0];
    const float* v_w    = (const float*)d_in[1];
    const float* v_b    = (const float*)d_in[2];
    const float* qd_w   = (const float*)d_in[3];
    const float* qd_b   = (const float*)d_in[4];
    const float* qs_w   = (const float*)d_in[5];
    const float* qw_w   = (const float*)d_in[6];
    const float* qw_b   = (const float*)d_in[7];
    const float* out_w  = (const float*)d_in[8];
    const float* out_b  = (const float*)d_in[9];
    const float* prior  = (const float*)d_in[10];
    const float* dscale = (const float*)d_in[11];
    float* out = (float*)d_out;

    char* ws = (char*)d_ws;
    unsigned short* xb    = (unsigned short*)(ws);                    // 8 MB
    unsigned short* v_bf  = (unsigned short*)(ws + 8388608);          // 8 MB (f16)
    unsigned short* vpad  = (unsigned short*)(ws + 16777216);         // 1 KB guard
    float*          proj  = (float*)(ws + 16778240);                  // ~21 MB
    unsigned short* mid   = (unsigned short*)(ws + 37749760);         // 8 MB (f16)
    unsigned short* Wt    = (unsigned short*)(ws + 46138368);         // 416 KB
    float*          biasD = (float*)(ws + 46564352);                  // 1.25 KB

    // Co-residency-safe grid: all stages are grid-stride, so any grid works.
    int maxBlocksPerCU = 0;
    hipOccupancyMaxActiveBlocksPerMultiprocessor(&maxBlocksPerCU, (const void*)mega, 256, 0);
    int grid = maxBlocksPerCU * 256;
    if (grid > NBMAX) grid = NBMAX;
    if (grid < 256)  grid = 256;   // defensive floor (still correct)

    void* args[] = {
        (void*)&x, (void*)&v_w, (void*)&v_b, (void*)&qd_w, (void*)&qd_b,
        (void*)&qs_w, (void*)&qw_w, (void*)&qw_b, (void*)&out_w, (void*)&out_b,
        (void*)&prior, (void*)&dscale, (void*)&out,
        (void*)&xb, (void*)&v_bf, (void*)&vpad, (void*)&proj, (void*)&mid,
        (void*)&Wt, (void*)&biasD
    };
    hipLaunchCooperativeKernel((const void*)mega, dim3(grid), dim3(256),
                               args, 0, stream);
}

// Round 11
// 408.322 us; speedup vs baseline: 1.0012x; 1.0012x over previous
//
#include <hip/hip_runtime.h>
#include <hip/hip_fp16.h>
#include <hip/hip_cooperative_groups.h>

namespace cg = cooperative_groups;

#define NPIX 16384
#define NBMAX 1024

typedef __attribute__((ext_vector_type(8))) short short8;
typedef __attribute__((ext_vector_type(8))) _Float16 half8;
typedef __attribute__((ext_vector_type(4))) float f32x4;

__device__ __forceinline__ unsigned short f2bf(float f) {
    unsigned u = __float_as_uint(f);
    unsigned r = (u + 0x7fffu + ((u >> 16) & 1u)) >> 16;
    return (unsigned short)r;
}
__device__ __forceinline__ unsigned short f2h_us(float f) {
    union { _Float16 h; unsigned short u; } cv;
    cv.h = (_Float16)f;
    return cv.u;
}
__device__ __forceinline__ unsigned hdup(float f) {
    unsigned short u = f2h_us(f);
    return (unsigned)u | ((unsigned)u << 16);
}
__device__ __forceinline__ unsigned hfma2u(unsigned w, unsigned v, unsigned a) {
    union { unsigned u; __half2 h; } W, V, A, R;
    W.u = w; V.u = v; A.u = a;
    R.h = __hfma2(W.h, V.h, A.h);
    return R.u;
}
__device__ __forceinline__ unsigned hadd2u(unsigned a, unsigned b) {
    union { unsigned u; __half2 h; } A, B, R;
    A.u = a; B.u = b;
    R.h = __hadd2(A.h, B.h);
    return R.u;
}

#define GLOAD16(SRC, DST) \
    __builtin_amdgcn_global_load_lds( \
        (const __attribute__((address_space(1))) unsigned*)(SRC), \
        (__attribute__((address_space(3))) unsigned*)(DST), 16, 0, 0)

// 32 KB LDS union -> 5 blocks/CU LDS-wise; VGPR<=128 via launch_bounds -> 4.
union SMem {
    struct { float t[64][65]; } prep;                        // 16640 B
    struct { unsigned short As[64 * 128], Bs[64 * 128]; } g; // 32768 B
    struct { int offs[576 * 2]; unsigned wpk[576 * 4]; } s;  // 13824 B
};

__device__ __forceinline__ float wsrc(int k, int n,
    const float* v_w, const float* qd_w, const float* qs_w,
    const float* qw_w, const float* out_w)
{
    if (n < 256) return v_w[k * 256 + n];
    n -= 256;
    if (n < 144) return qd_w[k * 144 + n];
    n -= 144;
    if (n < 72)  return qs_w[k * 72 + n];
    n -= 72;
    if (n < 72)  return qw_w[k * 72 + n];
    n -= 72;
    if (n < 32)  return 0.f;
    return out_w[k * 256 + (n - 32)];
}

// 64x64 tile, K=256 in two K=128 halves through 32 KB LDS. Rows of 128
// elems (256 B = 16 granules of 16 B), granule XOR-swizzled by (row&7).
template<bool F16>
__device__ __forceinline__ void gemm_tile(
    const unsigned short* __restrict__ Ab,   // [64][256] at row base
    const unsigned short* __restrict__ Bb,   // [64][256] at col base
    SMem* sm, int tid, f32x4* acc)
{
    const int wid  = tid >> 6;
    const int lane = tid & 63;
    const int wr = (wid >> 1) * 32;
    const int wc = (wid & 1) * 32;
    const int fr = lane & 15;
    const int fg = lane >> 4;
    const int ra0 = wr + fr, ra1 = ra0 + 16;
    const int rb0 = wc + fr, rb1 = rb0 + 16;
    const int sa  = ra0 & 7;
    const int sb  = rb0 & 7;

    #pragma unroll
    for (int kh = 0; kh < 2; ++kh) {
        __syncthreads();   // prior reads of LDS done
        #pragma unroll
        for (int it = 0; it < 4; ++it) {
            const int rr  = it * 16 + wid * 4 + (lane >> 4);
            const int gl  = lane & 15;
            const int gsw = gl ^ (rr & 7);
            GLOAD16(Ab + rr * 256 + kh * 128 + gsw * 8, &sm->g.As[(it * 16 + wid * 4) * 128]);
            GLOAD16(Bb + rr * 256 + kh * 128 + gsw * 8, &sm->g.Bs[(it * 16 + wid * 4) * 128]);
        }
        asm volatile("s_waitcnt vmcnt(0)" ::: "memory");
        __syncthreads();

        #pragma unroll
        for (int t = 0; t < 4; ++t) {
            const int gran = t * 4 + fg;
            if (F16) {
                half8 a0 = *(const half8*)&sm->g.As[ra0 * 128 + ((gran ^ sa) * 8)];
                half8 a1 = *(const half8*)&sm->g.As[ra1 * 128 + ((gran ^ sa) * 8)];
                half8 b0 = *(const half8*)&sm->g.Bs[rb0 * 128 + ((gran ^ sb) * 8)];
                half8 b1 = *(const half8*)&sm->g.Bs[rb1 * 128 + ((gran ^ sb) * 8)];
                acc[0] = __builtin_amdgcn_mfma_f32_16x16x32_f16(a0, b0, acc[0], 0, 0, 0);
                acc[1] = __builtin_amdgcn_mfma_f32_16x16x32_f16(a0, b1, acc[1], 0, 0, 0);
                acc[2] = __builtin_amdgcn_mfma_f32_16x16x32_f16(a1, b0, acc[2], 0, 0, 0);
                acc[3] = __builtin_amdgcn_mfma_f32_16x16x32_f16(a1, b1, acc[3], 0, 0, 0);
            } else {
                short8 a0 = *(const short8*)&sm->g.As[ra0 * 128 + ((gran ^ sa) * 8)];
                short8 a1 = *(const short8*)&sm->g.As[ra1 * 128 + ((gran ^ sa) * 8)];
                short8 b0 = *(const short8*)&sm->g.Bs[rb0 * 128 + ((gran ^ sb) * 8)];
                short8 b1 = *(const short8*)&sm->g.Bs[rb1 * 128 + ((gran ^ sb) * 8)];
                acc[0] = __builtin_amdgcn_mfma_f32_16x16x32_bf16(a0, b0, acc[0], 0, 0, 0);
                acc[1] = __builtin_amdgcn_mfma_f32_16x16x32_bf16(a0, b1, acc[1], 0, 0, 0);
                acc[2] = __builtin_amdgcn_mfma_f32_16x16x32_bf16(a1, b0, acc[2], 0, 0, 0);
                acc[3] = __builtin_amdgcn_mfma_f32_16x16x32_bf16(a1, b1, acc[3], 0, 0, 0);
            }
        }
    }
}

__global__ __launch_bounds__(256, 4) void mega(
    const float* __restrict__ x,
    const float* __restrict__ v_w, const float* __restrict__ v_b,
    const float* __restrict__ qd_w, const float* __restrict__ qd_b,
    const float* __restrict__ qs_w,
    const float* __restrict__ qw_w, const float* __restrict__ qw_b,
    const float* __restrict__ out_w, const float* __restrict__ out_b,
    const float* __restrict__ prior, const float* __restrict__ dscale,
    float* __restrict__ out,
    unsigned short* __restrict__ xb, unsigned short* __restrict__ v_bf,
    unsigned short* __restrict__ vpad, float* __restrict__ proj,
    unsigned short* __restrict__ mid, unsigned short* __restrict__ Wt,
    float* __restrict__ biasD)
{
    __shared__ SMem sm;
    cg::grid_group grid = cg::this_grid();
    const int tid = threadIdx.x;
    const int bid = blockIdx.x;
    const int nb  = gridDim.x;
    const int wid  = tid >> 6;
    const int lane = tid & 63;

    // ================= Stage P: x->bf16, Wt transpose, bias/pad ==========
    for (int chunk = bid; chunk < 2048; chunk += nb) {
        const size_t i = (size_t)chunk * 256 + tid;
        const float4 v0 = *(const float4*)(x + i * 8);
        const float4 v1 = *(const float4*)(x + i * 8 + 4);
        uint4 pk;
        pk.x = f2bf(v0.x) | ((unsigned)f2bf(v0.y) << 16);
        pk.y = f2bf(v0.z) | ((unsigned)f2bf(v0.w) << 16);
        pk.z = f2bf(v1.x) | ((unsigned)f2bf(v1.y) << 16);
        pk.w = f2bf(v1.z) | ((unsigned)f2bf(v1.w) << 16);
        *(uint4*)(xb + i * 8) = pk;
    }
    if (bid < 52) {
        const int tn = bid % 13;
        const int tk = bid / 13;
        #pragma unroll
        for (int i = 0; i < 16; ++i) {
            const int idx = tid + i * 256;
            const int r = idx >> 6;
            const int c = idx & 63;
            sm.prep.t[r][c] = wsrc(tk * 64 + r, tn * 64 + c, v_w, qd_w, qs_w, qw_w, out_w);
        }
        __syncthreads();
        const bool asF16 = (tn >= 9);
        #pragma unroll
        for (int i = 0; i < 8; ++i) {
            const int idx = tid + i * 256;
            const int rn = idx >> 5;
            const int cc = idx & 31;
            unsigned pk;
            if (asF16)
                pk = (unsigned)f2h_us(sm.prep.t[cc * 2][rn]) | ((unsigned)f2h_us(sm.prep.t[cc * 2 + 1][rn]) << 16);
            else
                pk = (unsigned)f2bf(sm.prep.t[cc * 2][rn]) | ((unsigned)f2bf(sm.prep.t[cc * 2 + 1][rn]) << 16);
            ((unsigned*)(Wt + (size_t)(tn * 64 + rn) * 256 + tk * 64))[cc] = pk;
        }
    }
    if (bid == 52) {
        for (int i = tid; i < 320; i += 256) {
            float bv = 0.f;
            if (i < 144)                  bv = qd_b[i];
            else if (i >= 216 && i < 288) bv = qw_b[i - 216];
            biasD[i] = bv;
        }
        for (int i = tid; i < 512; i += 256) vpad[i] = 0;
    }
    __threadfence();
    grid.sync();

    // ================= Stage G1: projection GEMM (2304 jobs) =============
    for (int job = bid; job < 2304; job += nb) {
        const int rt = job & 255;
        const int j  = job >> 8;
        const int row0 = rt * 64;

        f32x4 acc[4] = {{0,0,0,0},{0,0,0,0},{0,0,0,0},{0,0,0,0}};
        gemm_tile<false>(xb + (size_t)row0 * 256, Wt + (size_t)(j * 64) * 256,
                         &sm, tid, acc);

        const int wr = (wid >> 1) * 32;
        const int wc = (wid & 1) * 32;
        const int fr = lane & 15;
        const int fg = lane >> 4;
        if (j < 4) {
            const int colA = j * 64 + wc + fr;
            const int colB = colA + 16;
            const int gA = colA >> 5, cA = colA & 31;
            const int gB = colB >> 5, cB = colB & 31;
            const float biasA = v_b[colA];
            const float biasB = v_b[colB];
            #pragma unroll
            for (int jj = 0; jj < 4; ++jj) {
                const int r0a = row0 + wr + fg * 4 + jj;
                const int r1a = r0a + 16;
                const int b0i = r0a >> 12;
                const int hw0 = r0a & 4095, hw1 = r1a & 4095;
                v_bf[((size_t)(b0i * 8 + gA) * 4096 + hw0) * 32 + cA] = f2h_us(acc[0][jj] + biasA);
                v_bf[((size_t)(b0i * 8 + gB) * 4096 + hw0) * 32 + cB] = f2h_us(acc[1][jj] + biasB);
                v_bf[((size_t)(b0i * 8 + gA) * 4096 + hw1) * 32 + cA] = f2h_us(acc[2][jj] + biasA);
                v_bf[((size_t)(b0i * 8 + gB) * 4096 + hw1) * 32 + cB] = f2h_us(acc[3][jj] + biasB);
            }
        } else {
            const int colA = (j - 4) * 64 + wc + fr;
            const int colB = colA + 16;
            const float biasA = biasD[colA];
            const float biasB = biasD[colB];
            #pragma unroll
            for (int jj = 0; jj < 4; ++jj) {
                const int r0a = row0 + wr + fg * 4 + jj;
                const int r1a = r0a + 16;
                proj[(size_t)r0a * 320 + colA] = acc[0][jj] + biasA;
                proj[(size_t)r0a * 320 + colB] = acc[1][jj] + biasB;
                proj[(size_t)r1a * 320 + colA] = acc[2][jj] + biasA;
                proj[(size_t)r1a * 320 + colB] = acc[3][jj] + biasB;
            }
        }
    }
    __threadfence();
    grid.sync();

    // ================= Stage S: deformable sampling (2048 octets) ========
    for (int oct = bid; oct < 2048; oct += nb) {
        const int pix0 = oct * 8;
        __syncthreads();   // LDS reuse across octets / stages

        for (int it = tid; it < 576; it += 256) {
            const int p   = it / 72;
            const int rem = it - p * 72;
            const int g   = rem / 9;
            const int k   = rem - g * 9;
            const int pix = pix0 + p;
            const int b   = pix >> 12;
            const int hw  = pix & 4095;
            const int h   = hw >> 6, w = hw & 63;

            const float* row = proj + (size_t)pix * 320;
            const float qdx = row[g * 18 + k * 2 + 0];
            const float qdy = row[g * 18 + k * 2 + 1];
            const float s   = row[144 + g * 9 + k] + dscale[g];
            const float wt  = row[216 + g * 9 + k];
            const float sig6 = 6.0f / (1.0f + __expf(-s));
            const float px = (float)w + (qdx + prior[k * 2 + 0]) * sig6;
            const float py = (float)h + (qdy + prior[k * 2 + 1]) * sig6;

            const float x0f = floorf(px), y0f = floorf(py);
            const int ix = (int)x0f, iy = (int)y0f;
            const float wx1 = px - x0f, wx0 = 1.f - wx1;
            const float wy1 = py - y0f, wy0 = 1.f - wy1;
            const int plane = (b * 8 + g) << 12;

            const bool vy0 = (iy >= 0) & (iy < 64);
            const bool vy1 = (iy >= -1) & (iy < 63);
            const bool vx0 = (ix >= 0) & (ix < 64);
            const bool vx1 = (ix >= -1) & (ix < 63);
            const float w00 = (vy0 & vx0) ? wt * wy0 * wx0 : 0.f;
            const float w10 = (vy1 & vx0) ? wt * wy1 * wx0 : 0.f;
            const float w01 = (vy0 & vx1) ? wt * wy0 * wx1 : 0.f;
            const float w11 = (vy1 & vx1) ? wt * wy1 * wx1 : 0.f;
            sm.s.wpk[it * 4 + 0] = hdup(w00);
            sm.s.wpk[it * 4 + 1] = hdup(w10);
            sm.s.wpk[it * 4 + 2] = hdup(w01);
            sm.s.wpk[it * 4 + 3] = hdup(w11);

            const int xs  = min(max(ix,     -1), 63);
            const int y0c = min(max(iy,      0), 63);
            const int y1c = min(max(iy + 1,  0), 63);
            sm.s.offs[it * 2 + 0] = (plane + y0c * 64 + xs) * 64;   // bytes
            sm.s.offs[it * 2 + 1] = (plane + y1c * 64 + xs) * 64;
        }
        __syncthreads();

        const int p4 = tid >> 6;
        const int g  = (tid >> 3) & 7;
        const int q  = tid & 7;
        const int xh = q >> 2;
        const int qb = q * 16;
        const char* vbb = (const char*)v_bf;

        unsigned aA0=0,aA1=0,aA2=0,aA3=0, aB0=0,aB1=0,aB2=0,aB3=0;
        unsigned bA0=0,bA1=0,bA2=0,bA3=0, bB0=0,bB1=0,bB2=0,bB3=0;
        const int item0a = p4 * 72 + g * 9;
        const int item0b = (p4 + 4) * 72 + g * 9;

        #pragma unroll
        for (int k = 0; k < 9; ++k) {
            {
                const int it = item0a + k;
                const int2  o2 = *(const int2*)&sm.s.offs[it * 2];
                const uint2 wp = *(const uint2*)&sm.s.wpk[it * 4 + xh * 2];
                const uint4 r0 = *(const uint4*)(vbb + o2.x + qb);
                const uint4 r1 = *(const uint4*)(vbb + o2.y + qb);
                aA0 = hfma2u(wp.x, r0.x, aA0);
                aA1 = hfma2u(wp.x, r0.y, aA1);
                aA2 = hfma2u(wp.x, r0.z, aA2);
                aA3 = hfma2u(wp.x, r0.w, aA3);
                aB0 = hfma2u(wp.y, r1.x, aB0);
                aB1 = hfma2u(wp.y, r1.y, aB1);
                aB2 = hfma2u(wp.y, r1.z, aB2);
                aB3 = hfma2u(wp.y, r1.w, aB3);
            }
            {
                const int it = item0b + k;
                const int2  o2 = *(const int2*)&sm.s.offs[it * 2];
                const uint2 wp = *(const uint2*)&sm.s.wpk[it * 4 + xh * 2];
                const uint4 r0 = *(const uint4*)(vbb + o2.x + qb);
                const uint4 r1 = *(const uint4*)(vbb + o2.y + qb);
                bA0 = hfma2u(wp.x, r0.x, bA0);
                bA1 = hfma2u(wp.x, r0.y, bA1);
                bA2 = hfma2u(wp.x, r0.z, bA2);
                bA3 = hfma2u(wp.x, r0.w, bA3);
                bB0 = hfma2u(wp.y, r1.x, bB0);
                bB1 = hfma2u(wp.y, r1.y, bB1);
                bB2 = hfma2u(wp.y, r1.z, bB2);
                bB3 = hfma2u(wp.y, r1.w, bB3);
            }
        }

        uint4 oA, oB;
        {
            unsigned c;
            c = hadd2u(aA0, aB0); c = hadd2u(c, (unsigned)__shfl_xor((int)c, 4)); oA.x = c;
            c = hadd2u(aA1, aB1); c = hadd2u(c, (unsigned)__shfl_xor((int)c, 4)); oA.y = c;
            c = hadd2u(aA2, aB2); c = hadd2u(c, (unsigned)__shfl_xor((int)c, 4)); oA.z = c;
            c = hadd2u(aA3, aB3); c = hadd2u(c, (unsigned)__shfl_xor((int)c, 4)); oA.w = c;
            c = hadd2u(bA0, bB0); c = hadd2u(c, (unsigned)__shfl_xor((int)c, 4)); oB.x = c;
            c = hadd2u(bA1, bB1); c = hadd2u(c, (unsigned)__shfl_xor((int)c, 4)); oB.y = c;
            c = hadd2u(bA2, bB2); c = hadd2u(c, (unsigned)__shfl_xor((int)c, 4)); oB.z = c;
            c = hadd2u(bA3, bB3); c = hadd2u(c, (unsigned)__shfl_xor((int)c, 4)); oB.w = c;
        }
        if (xh == 0) {
            const int cq8 = (q & 3) * 8;
            *(uint4*)(mid + (size_t)(pix0 + p4) * 256 + g * 32 + cq8) = oA;
            *(uint4*)(mid + (size_t)(pix0 + p4 + 4) * 256 + g * 32 + cq8) = oB;
        }
    }
    __threadfence();
    grid.sync();

    // ================= Stage G2: output GEMM (1024 jobs) =================
    for (int job = bid; job < 1024; job += nb) {
        const int rt = job & 255;
        const int ct = job >> 8;
        const int row0 = rt * 64;
        const int col0 = ct * 64;

        f32x4 acc[4] = {{0,0,0,0},{0,0,0,0},{0,0,0,0},{0,0,0,0}};
        gemm_tile<true>(mid + (size_t)row0 * 256,
                        Wt + (size_t)(576 + col0) * 256, &sm, tid, acc);

        const int wr = (wid >> 1) * 32;
        const int wc = (wid & 1) * 32;
        const int fr = lane & 15;
        const int fg = lane >> 4;
        const int colA = col0 + wc + fr;
        const int colB = colA + 16;
        const float biasA = out_b[colA];
        const float biasB = out_b[colB];
        #pragma unroll
        for (int jj = 0; jj < 4; ++jj) {
            const int r0a = row0 + wr + fg * 4 + jj;
            const int r1a = r0a + 16;
            out[(size_t)r0a * 256 + colA] = acc[0][jj] + biasA;
            out[(size_t)r0a * 256 + colB] = acc[1][jj] + biasB;
            out[(size_t)r1a * 256 + colA] = acc[2][jj] + biasA;
            out[(size_t)r1a * 256 + colB] = acc[3][jj] + biasB;
        }
    }
}

// ---------------------------------------------------------------------------
extern "C" void kernel_launch(void* const* d_in, const int* in_sizes, int n_in,
                              void* d_out, int out_size, void* d_ws, size_t ws_size,
                              hipStream_t stream)
{
    (void)in_sizes; (void)n_in; (void)out_size; (void)ws_size;

    const float* x      = (const float*)d_in[0];
    const float* v_w    = (const float*)d_in[1];
    const float* v_b    = (const float*)d_in[2];
    const float* qd_w   = (const float*)d_in[3];
    const float* qd_b   = (const float*)d_in[4];
    const float* qs_w   = (const float*)d_in[5];
    const float* qw_w   = (const float*)d_in[6];
    const float* qw_b   = (const float*)d_in[7];
    const float* out_w  = (const float*)d_in[8];
    const float* out_b  = (const float*)d_in[9];
    const float* prior  = (const float*)d_in[10];
    const float* dscale = (const float*)d_in[11];
    float* out = (float*)d_out;

    char* ws = (char*)d_ws;
    unsigned short* xb    = (unsigned short*)(ws);                    // 8 MB
    unsigned short* v_bf  = (unsigned short*)(ws + 8388608);          // 8 MB (f16)
    unsigned short* vpad  = (unsigned short*)(ws + 16777216);         // 1 KB guard
    float*          proj  = (float*)(ws + 16778240);                  // ~21 MB
    unsigned short* mid   = (unsigned short*)(ws + 37749760);         // 8 MB (f16)
    unsigned short* Wt    = (unsigned short*)(ws + 46138368);         // 416 KB
    float*          biasD = (float*)(ws + 46564352);                  // 1.25 KB

    // Co-residency-safe grid: all stages are grid-stride, so any grid works.
    int maxBlocksPerCU = 0;
    hipOccupancyMaxActiveBlocksPerMultiprocessor(&maxBlocksPerCU, (const void*)mega, 256, 0);
    int grid = maxBlocksPerCU * 256;
    if (grid > NBMAX) grid = NBMAX;
    if (grid < 256)  grid = 256;   // defensive floor (still correct)

    void* args[] = {
        (void*)&x, (void*)&v_w, (void*)&v_b, (void*)&qd_w, (void*)&qd_b,
        (void*)&qs_w, (void*)&qw_w, (void*)&qw_b, (void*)&out_w, (void*)&out_b,
        (void*)&prior, (void*)&dscale, (void*)&out,
        (void*)&xb, (void*)&v_bf, (void*)&vpad, (void*)&proj, (void*)&mid,
        (void*)&Wt, (void*)&biasD
    };
    hipLaunchCooperativeKernel((const void*)mega, dim3(grid), dim3(256),
                               args, 0, stream);
}

// Round 12
// 408.120 us; speedup vs baseline: 1.0017x; 1.0005x over previous
//
#include <hip/hip_runtime.h>
#include <hip/hip_fp16.h>
#include <hip/hip_cooperative_groups.h>

namespace cg = cooperative_groups;

#define NPIX 16384
#define NBMAX 1024

typedef __attribute__((ext_vector_type(8))) short short8;
typedef __attribute__((ext_vector_type(8))) _Float16 half8;
typedef __attribute__((ext_vector_type(4))) float f32x4;

__device__ __forceinline__ unsigned short f2bf(float f) {
    unsigned u = __float_as_uint(f);
    unsigned r = (u + 0x7fffu + ((u >> 16) & 1u)) >> 16;
    return (unsigned short)r;
}
__device__ __forceinline__ unsigned short f2h_us(float f) {
    union { _Float16 h; unsigned short u; } cv;
    cv.h = (_Float16)f;
    return cv.u;
}
__device__ __forceinline__ unsigned hdup(float f) {
    unsigned short u = f2h_us(f);
    return (unsigned)u | ((unsigned)u << 16);
}
__device__ __forceinline__ unsigned hfma2u(unsigned w, unsigned v, unsigned a) {
    union { unsigned u; __half2 h; } W, V, A, R;
    W.u = w; V.u = v; A.u = a;
    R.h = __hfma2(W.h, V.h, A.h);
    return R.u;
}
__device__ __forceinline__ unsigned hadd2u(unsigned a, unsigned b) {
    union { unsigned u; __half2 h; } A, B, R;
    A.u = a; B.u = b;
    R.h = __hadd2(A.h, B.h);
    return R.u;
}

#define GLOAD16(SRC, DST) \
    __builtin_amdgcn_global_load_lds( \
        (const __attribute__((address_space(1))) unsigned*)(SRC), \
        (__attribute__((address_space(3))) unsigned*)(DST), 16, 0, 0)

// 32 KB LDS union -> 5 blocks/CU LDS-wise; VGPR<=128 via launch_bounds -> 4.
union SMem {
    struct { float t[64][65]; } prep;                        // 16640 B
    struct { unsigned short As[64 * 128], Bs[64 * 128]; } g; // 32768 B
    struct { int offs[576 * 2]; unsigned wpk[576 * 4]; } s;  // 13824 B
};

__device__ __forceinline__ float wsrc(int k, int n,
    const float* v_w, const float* qd_w, const float* qs_w,
    const float* qw_w, const float* out_w)
{
    if (n < 256) return v_w[k * 256 + n];
    n -= 256;
    if (n < 144) return qd_w[k * 144 + n];
    n -= 144;
    if (n < 72)  return qs_w[k * 72 + n];
    n -= 72;
    if (n < 72)  return qw_w[k * 72 + n];
    n -= 72;
    if (n < 32)  return 0.f;
    return out_w[k * 256 + (n - 32)];
}

// 64x64 tile, K=256 in two K=128 halves through 32 KB LDS. Rows of 128
// elems (256 B = 16 granules of 16 B), granule XOR-swizzled by (row&7).
template<bool F16>
__device__ __forceinline__ void gemm_tile(
    const unsigned short* __restrict__ Ab,   // [64][256] at row base
    const unsigned short* __restrict__ Bb,   // [64][256] at col base
    SMem* sm, int tid, f32x4* acc)
{
    const int wid  = tid >> 6;
    const int lane = tid & 63;
    const int wr = (wid >> 1) * 32;
    const int wc = (wid & 1) * 32;
    const int fr = lane & 15;
    const int fg = lane >> 4;
    const int ra0 = wr + fr, ra1 = ra0 + 16;
    const int rb0 = wc + fr, rb1 = rb0 + 16;
    const int sa  = ra0 & 7;
    const int sb  = rb0 & 7;

    #pragma unroll
    for (int kh = 0; kh < 2; ++kh) {
        __syncthreads();   // prior reads of LDS done
        #pragma unroll
        for (int it = 0; it < 4; ++it) {
            const int rr  = it * 16 + wid * 4 + (lane >> 4);
            const int gl  = lane & 15;
            const int gsw = gl ^ (rr & 7);
            GLOAD16(Ab + rr * 256 + kh * 128 + gsw * 8, &sm->g.As[(it * 16 + wid * 4) * 128]);
            GLOAD16(Bb + rr * 256 + kh * 128 + gsw * 8, &sm->g.Bs[(it * 16 + wid * 4) * 128]);
        }
        asm volatile("s_waitcnt vmcnt(0)" ::: "memory");
        __syncthreads();

        #pragma unroll
        for (int t = 0; t < 4; ++t) {
            const int gran = t * 4 + fg;
            if (F16) {
                half8 a0 = *(const half8*)&sm->g.As[ra0 * 128 + ((gran ^ sa) * 8)];
                half8 a1 = *(const half8*)&sm->g.As[ra1 * 128 + ((gran ^ sa) * 8)];
                half8 b0 = *(const half8*)&sm->g.Bs[rb0 * 128 + ((gran ^ sb) * 8)];
                half8 b1 = *(const half8*)&sm->g.Bs[rb1 * 128 + ((gran ^ sb) * 8)];
                acc[0] = __builtin_amdgcn_mfma_f32_16x16x32_f16(a0, b0, acc[0], 0, 0, 0);
                acc[1] = __builtin_amdgcn_mfma_f32_16x16x32_f16(a0, b1, acc[1], 0, 0, 0);
                acc[2] = __builtin_amdgcn_mfma_f32_16x16x32_f16(a1, b0, acc[2], 0, 0, 0);
                acc[3] = __builtin_amdgcn_mfma_f32_16x16x32_f16(a1, b1, acc[3], 0, 0, 0);
            } else {
                short8 a0 = *(const short8*)&sm->g.As[ra0 * 128 + ((gran ^ sa) * 8)];
                short8 a1 = *(const short8*)&sm->g.As[ra1 * 128 + ((gran ^ sa) * 8)];
                short8 b0 = *(const short8*)&sm->g.Bs[rb0 * 128 + ((gran ^ sb) * 8)];
                short8 b1 = *(const short8*)&sm->g.Bs[rb1 * 128 + ((gran ^ sb) * 8)];
                acc[0] = __builtin_amdgcn_mfma_f32_16x16x32_bf16(a0, b0, acc[0], 0, 0, 0);
                acc[1] = __builtin_amdgcn_mfma_f32_16x16x32_bf16(a0, b1, acc[1], 0, 0, 0);
                acc[2] = __builtin_amdgcn_mfma_f32_16x16x32_bf16(a1, b0, acc[2], 0, 0, 0);
                acc[3] = __builtin_amdgcn_mfma_f32_16x16x32_bf16(a1, b1, acc[3], 0, 0, 0);
            }
        }
    }
}

__global__ __launch_bounds__(256, 4) void mega(
    const float* __restrict__ x,
    const float* __restrict__ v_w, const float* __restrict__ v_b,
    const float* __restrict__ qd_w, const float* __restrict__ qd_b,
    const float* __restrict__ qs_w,
    const float* __restrict__ qw_w, const float* __restrict__ qw_b,
    const float* __restrict__ out_w, const float* __restrict__ out_b,
    const float* __restrict__ prior, const float* __restrict__ dscale,
    float* __restrict__ out,
    unsigned short* __restrict__ xb, unsigned short* __restrict__ v_bf,
    unsigned short* __restrict__ vpad, float* __restrict__ proj,
    unsigned short* __restrict__ mid, unsigned short* __restrict__ Wt,
    float* __restrict__ biasD)
{
    __shared__ SMem sm;
    cg::grid_group grid = cg::this_grid();
    const int tid = threadIdx.x;
    const int bid = blockIdx.x;
    const int nb  = gridDim.x;
    const int wid  = tid >> 6;
    const int lane = tid & 63;

    // ================= Stage P: x->bf16, Wt transpose, bias/pad ==========
    for (int chunk = bid; chunk < 2048; chunk += nb) {
        const size_t i = (size_t)chunk * 256 + tid;
        const float4 v0 = *(const float4*)(x + i * 8);
        const float4 v1 = *(const float4*)(x + i * 8 + 4);
        uint4 pk;
        pk.x = f2bf(v0.x) | ((unsigned)f2bf(v0.y) << 16);
        pk.y = f2bf(v0.z) | ((unsigned)f2bf(v0.w) << 16);
        pk.z = f2bf(v1.x) | ((unsigned)f2bf(v1.y) << 16);
        pk.w = f2bf(v1.z) | ((unsigned)f2bf(v1.w) << 16);
        *(uint4*)(xb + i * 8) = pk;
    }
    if (bid < 52) {
        const int tn = bid % 13;
        const int tk = bid / 13;
        #pragma unroll
        for (int i = 0; i < 16; ++i) {
            const int idx = tid + i * 256;
            const int r = idx >> 6;
            const int c = idx & 63;
            sm.prep.t[r][c] = wsrc(tk * 64 + r, tn * 64 + c, v_w, qd_w, qs_w, qw_w, out_w);
        }
        __syncthreads();
        const bool asF16 = (tn >= 9);
        #pragma unroll
        for (int i = 0; i < 8; ++i) {
            const int idx = tid + i * 256;
            const int rn = idx >> 5;
            const int cc = idx & 31;
            unsigned pk;
            if (asF16)
                pk = (unsigned)f2h_us(sm.prep.t[cc * 2][rn]) | ((unsigned)f2h_us(sm.prep.t[cc * 2 + 1][rn]) << 16);
            else
                pk = (unsigned)f2bf(sm.prep.t[cc * 2][rn]) | ((unsigned)f2bf(sm.prep.t[cc * 2 + 1][rn]) << 16);
            ((unsigned*)(Wt + (size_t)(tn * 64 + rn) * 256 + tk * 64))[cc] = pk;
        }
    }
    if (bid == 52) {
        for (int i = tid; i < 320; i += 256) {
            float bv = 0.f;
            if (i < 144)                  bv = qd_b[i];
            else if (i >= 216 && i < 288) bv = qw_b[i - 216];
            biasD[i] = bv;
        }
        for (int i = tid; i < 512; i += 256) vpad[i] = 0;
    }
    __threadfence();
    grid.sync();

    // ================= Stage G1: projection GEMM (2304 jobs) =============
    for (int job = bid; job < 2304; job += nb) {
        const int rt = job & 255;
        const int j  = job >> 8;
        const int row0 = rt * 64;

        f32x4 acc[4] = {{0,0,0,0},{0,0,0,0},{0,0,0,0},{0,0,0,0}};
        gemm_tile<false>(xb + (size_t)row0 * 256, Wt + (size_t)(j * 64) * 256,
                         &sm, tid, acc);

        const int wr = (wid >> 1) * 32;
        const int wc = (wid & 1) * 32;
        const int fr = lane & 15;
        const int fg = lane >> 4;
        if (j < 4) {
            const int colA = j * 64 + wc + fr;
            const int colB = colA + 16;
            const int gA = colA >> 5, cA = colA & 31;
            const int gB = colB >> 5, cB = colB & 31;
            const float biasA = v_b[colA];
            const float biasB = v_b[colB];
            #pragma unroll
            for (int jj = 0; jj < 4; ++jj) {
                const int r0a = row0 + wr + fg * 4 + jj;
                const int r1a = r0a + 16;
                const int b0i = r0a >> 12;
                const int hw0 = r0a & 4095, hw1 = r1a & 4095;
                v_bf[((size_t)(b0i * 8 + gA) * 4096 + hw0) * 32 + cA] = f2h_us(acc[0][jj] + biasA);
                v_bf[((size_t)(b0i * 8 + gB) * 4096 + hw0) * 32 + cB] = f2h_us(acc[1][jj] + biasB);
                v_bf[((size_t)(b0i * 8 + gA) * 4096 + hw1) * 32 + cA] = f2h_us(acc[2][jj] + biasA);
                v_bf[((size_t)(b0i * 8 + gB) * 4096 + hw1) * 32 + cB] = f2h_us(acc[3][jj] + biasB);
            }
        } else {
            const int colA = (j - 4) * 64 + wc + fr;
            const int colB = colA + 16;
            const float biasA = biasD[colA];
            const float biasB = biasD[colB];
            #pragma unroll
            for (int jj = 0; jj < 4; ++jj) {
                const int r0a = row0 + wr + fg * 4 + jj;
                const int r1a = r0a + 16;
                proj[(size_t)r0a * 320 + colA] = acc[0][jj] + biasA;
                proj[(size_t)r0a * 320 + colB] = acc[1][jj] + biasB;
                proj[(size_t)r1a * 320 + colA] = acc[2][jj] + biasA;
                proj[(size_t)r1a * 320 + colB] = acc[3][jj] + biasB;
            }
        }
    }
    __threadfence();
    grid.sync();

    // ================= Stage S: deformable sampling (2048 octets) ========
    for (int oct = bid; oct < 2048; oct += nb) {
        const int pix0 = oct * 8;
        __syncthreads();   // LDS reuse across octets / stages

        for (int it = tid; it < 576; it += 256) {
            const int p   = it / 72;
            const int rem = it - p * 72;
            const int g   = rem / 9;
            const int k   = rem - g * 9;
            const int pix = pix0 + p;
            const int b   = pix >> 12;
            const int hw  = pix & 4095;
            const int h   = hw >> 6, w = hw & 63;

            const float* row = proj + (size_t)pix * 320;
            const float qdx = row[g * 18 + k * 2 + 0];
            const float qdy = row[g * 18 + k * 2 + 1];
            const float s   = row[144 + g * 9 + k] + dscale[g];
            const float wt  = row[216 + g * 9 + k];
            const float sig6 = 6.0f / (1.0f + __expf(-s));
            const float px = (float)w + (qdx + prior[k * 2 + 0]) * sig6;
            const float py = (float)h + (qdy + prior[k * 2 + 1]) * sig6;

            const float x0f = floorf(px), y0f = floorf(py);
            const int ix = (int)x0f, iy = (int)y0f;
            const float wx1 = px - x0f, wx0 = 1.f - wx1;
            const float wy1 = py - y0f, wy0 = 1.f - wy1;
            const int plane = (b * 8 + g) << 12;

            const bool vy0 = (iy >= 0) & (iy < 64);
            const bool vy1 = (iy >= -1) & (iy < 63);
            const bool vx0 = (ix >= 0) & (ix < 64);
            const bool vx1 = (ix >= -1) & (ix < 63);
            const float w00 = (vy0 & vx0) ? wt * wy0 * wx0 : 0.f;
            const float w10 = (vy1 & vx0) ? wt * wy1 * wx0 : 0.f;
            const float w01 = (vy0 & vx1) ? wt * wy0 * wx1 : 0.f;
            const float w11 = (vy1 & vx1) ? wt * wy1 * wx1 : 0.f;
            sm.s.wpk[it * 4 + 0] = hdup(w00);
            sm.s.wpk[it * 4 + 1] = hdup(w10);
            sm.s.wpk[it * 4 + 2] = hdup(w01);
            sm.s.wpk[it * 4 + 3] = hdup(w11);

            const int xs  = min(max(ix,     -1), 63);
            const int y0c = min(max(iy,      0), 63);
            const int y1c = min(max(iy + 1,  0), 63);
            sm.s.offs[it * 2 + 0] = (plane + y0c * 64 + xs) * 64;   // bytes
            sm.s.offs[it * 2 + 1] = (plane + y1c * 64 + xs) * 64;
        }
        __syncthreads();

        const int p4 = tid >> 6;
        const int g  = (tid >> 3) & 7;
        const int q  = tid & 7;
        const int xh = q >> 2;
        const int qb = q * 16;
        const char* vbb = (const char*)v_bf;

        unsigned aA0=0,aA1=0,aA2=0,aA3=0, aB0=0,aB1=0,aB2=0,aB3=0;
        unsigned bA0=0,bA1=0,bA2=0,bA3=0, bB0=0,bB1=0,bB2=0,bB3=0;
        const int item0a = p4 * 72 + g * 9;
        const int item0b = (p4 + 4) * 72 + g * 9;

        #pragma unroll
        for (int k = 0; k < 9; ++k) {
            {
                const int it = item0a + k;
                const int2  o2 = *(const int2*)&sm.s.offs[it * 2];
                const uint2 wp = *(const uint2*)&sm.s.wpk[it * 4 + xh * 2];
                const uint4 r0 = *(const uint4*)(vbb + o2.x + qb);
                const uint4 r1 = *(const uint4*)(vbb + o2.y + qb);
                aA0 = hfma2u(wp.x, r0.x, aA0);
                aA1 = hfma2u(wp.x, r0.y, aA1);
                aA2 = hfma2u(wp.x, r0.z, aA2);
                aA3 = hfma2u(wp.x, r0.w, aA3);
                aB0 = hfma2u(wp.y, r1.x, aB0);
                aB1 = hfma2u(wp.y, r1.y, aB1);
                aB2 = hfma2u(wp.y, r1.z, aB2);
                aB3 = hfma2u(wp.y, r1.w, aB3);
            }
            {
                const int it = item0b + k;
                const int2  o2 = *(const int2*)&sm.s.offs[it * 2];
                const uint2 wp = *(const uint2*)&sm.s.wpk[it * 4 + xh * 2];
                const uint4 r0 = *(const uint4*)(vbb + o2.x + qb);
                const uint4 r1 = *(const uint4*)(vbb + o2.y + qb);
                bA0 = hfma2u(wp.x, r0.x, bA0);
                bA1 = hfma2u(wp.x, r0.y, bA1);
                bA2 = hfma2u(wp.x, r0.z, bA2);
                bA3 = hfma2u(wp.x, r0.w, bA3);
                bB0 = hfma2u(wp.y, r1.x, bB0);
                bB1 = hfma2u(wp.y, r1.y, bB1);
                bB2 = hfma2u(wp.y, r1.z, bB2);
                bB3 = hfma2u(wp.y, r1.w, bB3);
            }
        }

        uint4 oA, oB;
        {
            unsigned c;
            c = hadd2u(aA0, aB0); c = hadd2u(c, (unsigned)__shfl_xor((int)c, 4)); oA.x = c;
            c = hadd2u(aA1, aB1); c = hadd2u(c, (unsigned)__shfl_xor((int)c, 4)); oA.y = c;
            c = hadd2u(aA2, aB2); c = hadd2u(c, (unsigned)__shfl_xor((int)c, 4)); oA.z = c;
            c = hadd2u(aA3, aB3); c = hadd2u(c, (unsigned)__shfl_xor((int)c, 4)); oA.w = c;
            c = hadd2u(bA0, bB0); c = hadd2u(c, (unsigned)__shfl_xor((int)c, 4)); oB.x = c;
            c = hadd2u(bA1, bB1); c = hadd2u(c, (unsigned)__shfl_xor((int)c, 4)); oB.y = c;
            c = hadd2u(bA2, bB2); c = hadd2u(c, (unsigned)__shfl_xor((int)c, 4)); oB.z = c;
            c = hadd2u(bA3, bB3); c = hadd2u(c, (unsigned)__shfl_xor((int)c, 4)); oB.w = c;
        }
        if (xh == 0) {
            const int cq8 = (q & 3) * 8;
            *(uint4*)(mid + (size_t)(pix0 + p4) * 256 + g * 32 + cq8) = oA;
            *(uint4*)(mid + (size_t)(pix0 + p4 + 4) * 256 + g * 32 + cq8) = oB;
        }
    }
    __threadfence();
    grid.sync();

    // ================= Stage G2: output GEMM (1024 jobs) =================
    for (int job = bid; job < 1024; job += nb) {
        const int rt = job & 255;
        const int ct = job >> 8;
        const int row0 = rt * 64;
        const int col0 = ct * 64;

        f32x4 acc[4] = {{0,0,0,0},{0,0,0,0},{0,0,0,0},{0,0,0,0}};
        gemm_tile<true>(mid + (size_t)row0 * 256,
                        Wt + (size_t)(576 + col0) * 256, &sm, tid, acc);

        const int wr = (wid >> 1) * 32;
        const int wc = (wid & 1) * 32;
        const int fr = lane & 15;
        const int fg = lane >> 4;
        const int colA = col0 + wc + fr;
        const int colB = colA + 16;
        const float biasA = out_b[colA];
        const float biasB = out_b[colB];
        #pragma unroll
        for (int jj = 0; jj < 4; ++jj) {
            const int r0a = row0 + wr + fg * 4 + jj;
            const int r1a = r0a + 16;
            out[(size_t)r0a * 256 + colA] = acc[0][jj] + biasA;
            out[(size_t)r0a * 256 + colB] = acc[1][jj] + biasB;
            out[(size_t)r1a * 256 + colA] = acc[2][jj] + biasA;
            out[(size_t)r1a * 256 + colB] = acc[3][jj] + biasB;
        }
    }
}

// ---------------------------------------------------------------------------
extern "C" void kernel_launch(void* const* d_in, const int* in_sizes, int n_in,
                              void* d_out, int out_size, void* d_ws, size_t ws_size,
                              hipStream_t stream)
{
    (void)in_sizes; (void)n_in; (void)out_size; (void)ws_size;

    const float* x      = (const float*)d_in[0];
    const float* v_w    = (const float*)d_in[1];
    const float* v_b    = (const float*)d_in[2];
    const float* qd_w   = (const float*)d_in[3];
    const float* qd_b   = (const float*)d_in[4];
    const float* qs_w   = (const float*)d_in[5];
    const float* qw_w   = (const float*)d_in[6];
    const float* qw_b   = (const float*)d_in[7];
    const float* out_w  = (const float*)d_in[8];
    const float* out_b  = (const float*)d_in[9];
    const float* prior  = (const float*)d_in[10];
    const float* dscale = (const float*)d_in[11];
    float* out = (float*)d_out;

    char* ws = (char*)d_ws;
    unsigned short* xb    = (unsigned short*)(ws);                    // 8 MB
    unsigned short* v_bf  = (unsigned short*)(ws + 8388608);          // 8 MB (f16)
    unsigned short* vpad  = (unsigned short*)(ws + 16777216);         // 1 KB guard
    float*          proj  = (float*)(ws + 16778240);                  // ~21 MB
    unsigned short* mid   = (unsigned short*)(ws + 37749760);         // 8 MB (f16)
    unsigned short* Wt    = (unsigned short*)(ws + 46138368);         // 416 KB
    float*          biasD = (float*)(ws + 46564352);                  // 1.25 KB

    // Co-residency-safe grid: all stages are grid-stride, so any grid works.
    int maxBlocksPerCU = 0;
    hipOccupancyMaxActiveBlocksPerMultiprocessor(&maxBlocksPerCU, (const void*)mega, 256, 0);
    int grid = maxBlocksPerCU * 256;
    if (grid > NBMAX) grid = NBMAX;
    if (grid < 256)  grid = 256;   // defensive floor (still correct)

    void* args[] = {
        (void*)&x, (void*)&v_w, (void*)&v_b, (void*)&qd_w, (void*)&qd_b,
        (void*)&qs_w, (void*)&qw_w, (void*)&qw_b, (void*)&out_w, (void*)&out_b,
        (void*)&prior, (void*)&dscale, (void*)&out,
        (void*)&xb, (void*)&v_bf, (void*)&vpad, (void*)&proj, (void*)&mid,
        (void*)&Wt, (void*)&biasD
    };
    hipLaunchCooperativeKernel((const void*)mega, dim3(grid), dim3(256),
                               args, 0, stream);
}

// Round 13
// 56.474 us; speedup vs baseline: 7.2386x; 7.2266x over previous
//
#include <hip/hip_runtime.h>
#include <hip/hip_fp16.h>

#define NPIX 16384

typedef __attribute__((ext_vector_type(8))) short short8;
typedef __attribute__((ext_vector_type(8))) _Float16 half8;
typedef __attribute__((ext_vector_type(4))) float f32x4;

__device__ __forceinline__ unsigned short f2bf(float f) {
    unsigned u = __float_as_uint(f);
    unsigned r = (u + 0x7fffu + ((u >> 16) & 1u)) >> 16;
    return (unsigned short)r;
}
__device__ __forceinline__ unsigned short f2h_us(float f) {
    union { _Float16 h; unsigned short u; } cv;
    cv.h = (_Float16)f;
    return cv.u;
}
__device__ __forceinline__ unsigned hdup(float f) {
    unsigned short u = f2h_us(f);
    return (unsigned)u | ((unsigned)u << 16);
}
__device__ __forceinline__ unsigned hfma2u(unsigned w, unsigned v, unsigned a) {
    union { unsigned u; __half2 h; } W, V, A, R;
    W.u = w; V.u = v; A.u = a;
    R.h = __hfma2(W.h, V.h, A.h);
    return R.u;
}
__device__ __forceinline__ unsigned hadd2u(unsigned a, unsigned b) {
    union { unsigned u; __half2 h; } A, B, R;
    A.u = a; B.u = b;
    R.h = __hadd2(A.h, B.h);
    return R.u;
}

#define GLOAD16(SRC, DST) \
    __builtin_amdgcn_global_load_lds( \
        (const __attribute__((address_space(1))) unsigned*)(SRC), \
        (__attribute__((address_space(3))) unsigned*)(DST), 16, 0, 0)

// ---------------------------------------------------------------------------
// prep_all: blocks 0..2047 x->bf16 (XCD-aligned); 2048..2099 Wt transpose;
// 2100 biasD+pad. Wt n-rows: 0-255 v_w | 256-399 qd_w | 400-471 qs_w |
// 472-543 qw_w | 544-575 zero | 576-831 out_w (f16; rest bf16).
// ---------------------------------------------------------------------------
__device__ __forceinline__ float wsrc(int k, int n,
    const float* v_w, const float* qd_w, const float* qs_w,
    const float* qw_w, const float* out_w)
{
    if (n < 256) return v_w[k * 256 + n];
    n -= 256;
    if (n < 144) return qd_w[k * 144 + n];
    n -= 144;
    if (n < 72)  return qs_w[k * 72 + n];
    n -= 72;
    if (n < 72)  return qw_w[k * 72 + n];
    n -= 72;
    if (n < 32)  return 0.f;
    return out_w[k * 256 + (n - 32)];
}

__global__ __launch_bounds__(256) void prep_all(
    const float* __restrict__ x, unsigned short* __restrict__ xb,
    const float* __restrict__ v_w, const float* __restrict__ qd_w,
    const float* __restrict__ qs_w, const float* __restrict__ qw_w,
    const float* __restrict__ out_w, const float* __restrict__ qd_b,
    const float* __restrict__ qw_b,
    unsigned short* __restrict__ Wt, float* __restrict__ biasD,
    unsigned short* __restrict__ vpad)
{
    __shared__ float t[64][65];
    const int bid = blockIdx.x;
    const int tid = threadIdx.x;

    if (bid < 2048) {
        const int bb = (bid >> 3) + (bid & 7) * 256;
        const size_t i = (size_t)bb * 256 + tid;
        const float4 v0 = *(const float4*)(x + i * 8);
        const float4 v1 = *(const float4*)(x + i * 8 + 4);
        uint4 pk;
        pk.x = f2bf(v0.x) | ((unsigned)f2bf(v0.y) << 16);
        pk.y = f2bf(v0.z) | ((unsigned)f2bf(v0.w) << 16);
        pk.z = f2bf(v1.x) | ((unsigned)f2bf(v1.y) << 16);
        pk.w = f2bf(v1.z) | ((unsigned)f2bf(v1.w) << 16);
        *(uint4*)(xb + i * 8) = pk;
        return;
    }
    if (bid == 2100) {
        for (int i = tid; i < 320; i += 256) {
            float bv = 0.f;
            if (i < 144)                  bv = qd_b[i];
            else if (i >= 216 && i < 288) bv = qw_b[i - 216];
            biasD[i] = bv;
        }
        for (int i = tid; i < 512; i += 256) vpad[i] = 0;
        return;
    }
    const int tile = bid - 2048;
    const int tn = tile % 13;
    const int tk = tile / 13;
    #pragma unroll
    for (int i = 0; i < 16; ++i) {
        const int idx = tid + i * 256;
        const int r = idx >> 6;
        const int c = idx & 63;
        t[r][c] = wsrc(tk * 64 + r, tn * 64 + c, v_w, qd_w, qs_w, qw_w, out_w);
    }
    __syncthreads();
    const bool asF16 = (tn >= 9);
    #pragma unroll
    for (int i = 0; i < 8; ++i) {
        const int idx = tid + i * 256;
        const int rn = idx >> 5;
        const int cc = idx & 31;
        unsigned pk;
        if (asF16)
            pk = (unsigned)f2h_us(t[cc * 2][rn]) | ((unsigned)f2h_us(t[cc * 2 + 1][rn]) << 16);
        else
            pk = (unsigned)f2bf(t[cc * 2][rn]) | ((unsigned)f2bf(t[cc * 2 + 1][rn]) << 16);
        ((unsigned*)(Wt + (size_t)(tn * 64 + rn) * 256 + tk * 64))[cc] = pk;
    }
}

// ---------------------------------------------------------------------------
// gemm_proj: [NPIX][256]bf16 @ Wt[j*64..][256]^T, j=0..8. XCD-remapped rows.
//   j<4  -> v_bf F16 GROUP-MAJOR [b][g][4096][32];  j>=4 -> proj f32 [NPIX][320]
// ---------------------------------------------------------------------------
__global__ __launch_bounds__(256) void gemm_proj(
    const unsigned short* __restrict__ A, const unsigned short* __restrict__ Wt,
    const float* __restrict__ v_b, const float* __restrict__ biasD,
    unsigned short* __restrict__ v_bf, float* __restrict__ proj)
{
    __shared__ unsigned short As[64 * 256];
    __shared__ unsigned short Bs[64 * 256];

    const int tid  = threadIdx.x;
    const int wid  = tid >> 6;
    const int lane = tid & 63;
    const int bx   = blockIdx.x;
    const int tile = (bx >> 3) + (bx & 7) * 32;
    const int row0 = tile * 64;
    const int j    = blockIdx.y;

    const unsigned short* Ab = A  + (size_t)row0 * 256;
    const unsigned short* Bb = Wt + (size_t)(j * 64) * 256;
    const int rl = lane >> 5;
    const int gl = lane & 31;

    #pragma unroll
    for (int it = 0; it < 8; ++it) {
        const int r   = wid * 16 + it * 2 + rl;
        const int gsw = gl ^ (r & 7);
        GLOAD16(Ab + r * 256 + gsw * 8, &As[(wid * 16 + it * 2) * 256]);
        GLOAD16(Bb + r * 256 + gsw * 8, &Bs[(wid * 16 + it * 2) * 256]);
    }
    asm volatile("s_waitcnt vmcnt(0)" ::: "memory");
    __syncthreads();

    f32x4 acc00 = {0,0,0,0}, acc01 = {0,0,0,0};
    f32x4 acc10 = {0,0,0,0}, acc11 = {0,0,0,0};

    const int wr = (wid >> 1) * 32;
    const int wc = (wid & 1) * 32;
    const int fr = lane & 15;
    const int fg = lane >> 4;

    const int ra0 = wr + fr, ra1 = ra0 + 16;
    const int rb0 = wc + fr, rb1 = rb0 + 16;
    const int sa  = ra0 & 7;
    const int sb  = rb0 & 7;

    #pragma unroll
    for (int t = 0; t < 8; ++t) {
        const int gran = t * 4 + fg;
        short8 a0 = *(const short8*)&As[ra0 * 256 + (gran ^ sa) * 8];
        short8 a1 = *(const short8*)&As[ra1 * 256 + (gran ^ sa) * 8];
        short8 b0 = *(const short8*)&Bs[rb0 * 256 + (gran ^ sb) * 8];
        short8 b1 = *(const short8*)&Bs[rb1 * 256 + (gran ^ sb) * 8];
        acc00 = __builtin_amdgcn_mfma_f32_16x16x32_bf16(a0, b0, acc00, 0, 0, 0);
        acc01 = __builtin_amdgcn_mfma_f32_16x16x32_bf16(a0, b1, acc01, 0, 0, 0);
        acc10 = __builtin_amdgcn_mfma_f32_16x16x32_bf16(a1, b0, acc10, 0, 0, 0);
        acc11 = __builtin_amdgcn_mfma_f32_16x16x32_bf16(a1, b1, acc11, 0, 0, 0);
    }

    if (j < 4) {
        const int colA = j * 64 + wc + fr;
        const int colB = colA + 16;
        const int gA = colA >> 5, cA = colA & 31;
        const int gB = colB >> 5, cB = colB & 31;
        const float biasA = v_b[colA];
        const float biasB = v_b[colB];
        #pragma unroll
        for (int jj = 0; jj < 4; ++jj) {
            const int r0a = row0 + wr + fg * 4 + jj;
            const int r1a = r0a + 16;
            const int b0i = r0a >> 12;
            const int hw0 = r0a & 4095, hw1 = r1a & 4095;
            v_bf[((size_t)(b0i * 8 + gA) * 4096 + hw0) * 32 + cA] = f2h_us(acc00[jj] + biasA);
            v_bf[((size_t)(b0i * 8 + gB) * 4096 + hw0) * 32 + cB] = f2h_us(acc01[jj] + biasB);
            v_bf[((size_t)(b0i * 8 + gA) * 4096 + hw1) * 32 + cA] = f2h_us(acc10[jj] + biasA);
            v_bf[((size_t)(b0i * 8 + gB) * 4096 + hw1) * 32 + cB] = f2h_us(acc11[jj] + biasB);
        }
    } else {
        const int colA = (j - 4) * 64 + wc + fr;
        const int colB = colA + 16;
        const float biasA = biasD[colA];
        const float biasB = biasD[colB];
        #pragma unroll
        for (int jj = 0; jj < 4; ++jj) {
            const int r0a = row0 + wr + fg * 4 + jj;
            const int r1a = r0a + 16;
            proj[(size_t)r0a * 320 + colA] = acc00[jj] + biasA;
            proj[(size_t)r0a * 320 + colB] = acc01[jj] + biasB;
            proj[(size_t)r1a * 320 + colA] = acc10[jj] + biasA;
            proj[(size_t)r1a * 320 + colB] = acc11[jj] + biasB;
        }
    }
}

// ---------------------------------------------------------------------------
// gemm_out: out[M][256] = mid[M][256](f16) @ WtO(f16)^T + out_b (f32 out).
// ---------------------------------------------------------------------------
__global__ __launch_bounds__(256) void gemm_out(
    const unsigned short* __restrict__ A, const unsigned short* __restrict__ WtO,
    const float* __restrict__ bias, float* __restrict__ Y)
{
    __shared__ unsigned short As[64 * 256];
    __shared__ unsigned short Bs[64 * 256];

    const int tid  = threadIdx.x;
    const int wid  = tid >> 6;
    const int lane = tid & 63;
    const int bx   = blockIdx.x;
    const int tile = (bx >> 3) + (bx & 7) * 32;
    const int row0 = tile * 64;
    const int col0 = blockIdx.y * 64;

    const unsigned short* Ab = A   + (size_t)row0 * 256;
    const unsigned short* Bb = WtO + (size_t)col0 * 256;
    const int rl = lane >> 5;
    const int gl = lane & 31;

    #pragma unroll
    for (int it = 0; it < 8; ++it) {
        const int r   = wid * 16 + it * 2 + rl;
        const int gsw = gl ^ (r & 7);
        GLOAD16(Ab + r * 256 + gsw * 8, &As[(wid * 16 + it * 2) * 256]);
        GLOAD16(Bb + r * 256 + gsw * 8, &Bs[(wid * 16 + it * 2) * 256]);
    }
    asm volatile("s_waitcnt vmcnt(0)" ::: "memory");
    __syncthreads();

    f32x4 acc00 = {0,0,0,0}, acc01 = {0,0,0,0};
    f32x4 acc10 = {0,0,0,0}, acc11 = {0,0,0,0};

    const int wr = (wid >> 1) * 32;
    const int wc = (wid & 1) * 32;
    const int fr = lane & 15;
    const int fg = lane >> 4;

    const int ra0 = wr + fr, ra1 = ra0 + 16;
    const int rb0 = wc + fr, rb1 = rb0 + 16;
    const int sa  = ra0 & 7;
    const int sb  = rb0 & 7;

    #pragma unroll
    for (int t = 0; t < 8; ++t) {
        const int gran = t * 4 + fg;
        half8 a0 = *(const half8*)&As[ra0 * 256 + (gran ^ sa) * 8];
        half8 a1 = *(const half8*)&As[ra1 * 256 + (gran ^ sa) * 8];
        half8 b0 = *(const half8*)&Bs[rb0 * 256 + (gran ^ sb) * 8];
        half8 b1 = *(const half8*)&Bs[rb1 * 256 + (gran ^ sb) * 8];
        acc00 = __builtin_amdgcn_mfma_f32_16x16x32_f16(a0, b0, acc00, 0, 0, 0);
        acc01 = __builtin_amdgcn_mfma_f32_16x16x32_f16(a0, b1, acc01, 0, 0, 0);
        acc10 = __builtin_amdgcn_mfma_f32_16x16x32_f16(a1, b0, acc10, 0, 0, 0);
        acc11 = __builtin_amdgcn_mfma_f32_16x16x32_f16(a1, b1, acc11, 0, 0, 0);
    }

    const int colA = col0 + wc + fr;
    const int colB = colA + 16;
    const float biasA = bias[colA];
    const float biasB = bias[colB];
    #pragma unroll
    for (int jj = 0; jj < 4; ++jj) {
        const int r0a = row0 + wr + fg * 4 + jj;
        const int r1a = r0a + 16;
        Y[(size_t)r0a * 256 + colA] = acc00[jj] + biasA;
        Y[(size_t)r0a * 256 + colB] = acc01[jj] + biasB;
        Y[(size_t)r1a * 256 + colA] = acc10[jj] + biasA;
        Y[(size_t)r1a * 256 + colB] = acc11[jj] + biasB;
    }
}

// ---------------------------------------------------------------------------
// Sampler v7: v6 minus the projs LDS staging (proj read direct from global,
// L2-resident). LDS = 13.8 KB -> wave-cap occupancy: 8 blocks/CU, entire
// 2048-block grid co-resident (256 CU x 8). Everything else identical to v6.
// ---------------------------------------------------------------------------
__global__ __launch_bounds__(256) void dcn_sample7(
    const unsigned short* __restrict__ vbuf,  // [4][8][4096][32] f16
    const float* __restrict__ proj,           // [NPIX][320]
    const float* __restrict__ prior,          // [K][2]
    const float* __restrict__ dscale,         // [G]
    unsigned short* __restrict__ mid)         // [NPIX][256] f16
{
    __shared__ int      offs[576 * 2];   //  4608 B
    __shared__ unsigned wpk [576 * 4];   //  9216 B

    const int tid = threadIdx.x;
    const int bid  = blockIdx.x;
    const int wg   = (bid & 7) * 256 + (bid >> 3);
    const int pix0 = wg * 8;

    for (int it = tid; it < 576; it += 256) {
        const int p   = it / 72;
        const int rem = it - p * 72;
        const int g   = rem / 9;
        const int k   = rem - g * 9;
        const int pix = pix0 + p;
        const int b   = pix >> 12;
        const int hw  = pix & 4095;
        const int h   = hw >> 6, w = hw & 63;

        const float* row = proj + (size_t)pix * 320;
        const float qdx = row[g * 18 + k * 2 + 0];
        const float qdy = row[g * 18 + k * 2 + 1];
        const float s   = row[144 + g * 9 + k] + dscale[g];
        const float wt  = row[216 + g * 9 + k];
        const float sig6 = 6.0f / (1.0f + __expf(-s));
        const float px = (float)w + (qdx + prior[k * 2 + 0]) * sig6;
        const float py = (float)h + (qdy + prior[k * 2 + 1]) * sig6;

        const float x0f = floorf(px), y0f = floorf(py);
        const int ix = (int)x0f, iy = (int)y0f;
        const float wx1 = px - x0f, wx0 = 1.f - wx1;
        const float wy1 = py - y0f, wy0 = 1.f - wy1;
        const int plane = (b * 8 + g) << 12;

        const bool vy0 = (iy >= 0) & (iy < 64);
        const bool vy1 = (iy >= -1) & (iy < 63);
        const bool vx0 = (ix >= 0) & (ix < 64);
        const bool vx1 = (ix >= -1) & (ix < 63);
        const float w00 = (vy0 & vx0) ? wt * wy0 * wx0 : 0.f;
        const float w10 = (vy1 & vx0) ? wt * wy1 * wx0 : 0.f;
        const float w01 = (vy0 & vx1) ? wt * wy0 * wx1 : 0.f;
        const float w11 = (vy1 & vx1) ? wt * wy1 * wx1 : 0.f;
        wpk[it * 4 + 0] = hdup(w00);
        wpk[it * 4 + 1] = hdup(w10);
        wpk[it * 4 + 2] = hdup(w01);
        wpk[it * 4 + 3] = hdup(w11);

        const int xs  = min(max(ix,     -1), 63);
        const int y0c = min(max(iy,      0), 63);
        const int y1c = min(max(iy + 1,  0), 63);
        offs[it * 2 + 0] = (plane + y0c * 64 + xs) * 64;   // BYTE offsets
        offs[it * 2 + 1] = (plane + y1c * 64 + xs) * 64;
    }
    __syncthreads();

    const int p4 = tid >> 6;
    const int g  = (tid >> 3) & 7;
    const int q  = tid & 7;
    const int xh = q >> 2;
    const int qb = q * 16;
    const char* vbb = (const char*)vbuf;

    unsigned aA0=0,aA1=0,aA2=0,aA3=0, aB0=0,aB1=0,aB2=0,aB3=0;
    unsigned bA0=0,bA1=0,bA2=0,bA3=0, bB0=0,bB1=0,bB2=0,bB3=0;
    const int item0a = p4 * 72 + g * 9;
    const int item0b = (p4 + 4) * 72 + g * 9;

    #pragma unroll
    for (int k = 0; k < 9; ++k) {
        {
            const int it = item0a + k;
            const int2  o2 = *(const int2*)&offs[it * 2];
            const uint2 wp = *(const uint2*)&wpk[it * 4 + xh * 2];
            const uint4 r0 = *(const uint4*)(vbb + o2.x + qb);
            const uint4 r1 = *(const uint4*)(vbb + o2.y + qb);
            aA0 = hfma2u(wp.x, r0.x, aA0);
            aA1 = hfma2u(wp.x, r0.y, aA1);
            aA2 = hfma2u(wp.x, r0.z, aA2);
            aA3 = hfma2u(wp.x, r0.w, aA3);
            aB0 = hfma2u(wp.y, r1.x, aB0);
            aB1 = hfma2u(wp.y, r1.y, aB1);
            aB2 = hfma2u(wp.y, r1.z, aB2);
            aB3 = hfma2u(wp.y, r1.w, aB3);
        }
        {
            const int it = item0b + k;
            const int2  o2 = *(const int2*)&offs[it * 2];
            const uint2 wp = *(const uint2*)&wpk[it * 4 + xh * 2];
            const uint4 r0 = *(const uint4*)(vbb + o2.x + qb);
            const uint4 r1 = *(const uint4*)(vbb + o2.y + qb);
            bA0 = hfma2u(wp.x, r0.x, bA0);
            bA1 = hfma2u(wp.x, r0.y, bA1);
            bA2 = hfma2u(wp.x, r0.z, bA2);
            bA3 = hfma2u(wp.x, r0.w, bA3);
            bB0 = hfma2u(wp.y, r1.x, bB0);
            bB1 = hfma2u(wp.y, r1.y, bB1);
            bB2 = hfma2u(wp.y, r1.z, bB2);
            bB3 = hfma2u(wp.y, r1.w, bB3);
        }
    }

    uint4 oA, oB;
    {
        unsigned c;
        c = hadd2u(aA0, aB0); c = hadd2u(c, (unsigned)__shfl_xor((int)c, 4)); oA.x = c;
        c = hadd2u(aA1, aB1); c = hadd2u(c, (unsigned)__shfl_xor((int)c, 4)); oA.y = c;
        c = hadd2u(aA2, aB2); c = hadd2u(c, (unsigned)__shfl_xor((int)c, 4)); oA.z = c;
        c = hadd2u(aA3, aB3); c = hadd2u(c, (unsigned)__shfl_xor((int)c, 4)); oA.w = c;
        c = hadd2u(bA0, bB0); c = hadd2u(c, (unsigned)__shfl_xor((int)c, 4)); oB.x = c;
        c = hadd2u(bA1, bB1); c = hadd2u(c, (unsigned)__shfl_xor((int)c, 4)); oB.y = c;
        c = hadd2u(bA2, bB2); c = hadd2u(c, (unsigned)__shfl_xor((int)c, 4)); oB.z = c;
        c = hadd2u(bA3, bB3); c = hadd2u(c, (unsigned)__shfl_xor((int)c, 4)); oB.w = c;
    }
    if (xh == 0) {
        const int cq8 = (q & 3) * 8;
        *(uint4*)(mid + (size_t)(pix0 + p4) * 256 + g * 32 + cq8) = oA;
        *(uint4*)(mid + (size_t)(pix0 + p4 + 4) * 256 + g * 32 + cq8) = oB;
    }
}

// ---------------------------------------------------------------------------
extern "C" void kernel_launch(void* const* d_in, const int* in_sizes, int n_in,
                              void* d_out, int out_size, void* d_ws, size_t ws_size,
                              hipStream_t stream)
{
    (void)in_sizes; (void)n_in; (void)out_size; (void)ws_size;

    const float* x      = (const float*)d_in[0];
    const float* v_w    = (const float*)d_in[1];
    const float* v_b    = (const float*)d_in[2];
    const float* qd_w   = (const float*)d_in[3];
    const float* qd_b   = (const float*)d_in[4];
    const float* qs_w   = (const float*)d_in[5];
    const float* qw_w   = (const float*)d_in[6];
    const float* qw_b   = (const float*)d_in[7];
    const float* out_w  = (const float*)d_in[8];
    const float* out_b  = (const float*)d_in[9];
    const float* prior  = (const float*)d_in[10];
    const float* dscale = (const float*)d_in[11];
    float* out = (float*)d_out;

    char* ws = (char*)d_ws;
    unsigned short* xb    = (unsigned short*)(ws);                    // 8 MB
    unsigned short* v_bf  = (unsigned short*)(ws + 8388608);          // 8 MB (f16)
    unsigned short* vpad  = (unsigned short*)(ws + 16777216);         // 1 KB guard
    float*          proj  = (float*)(ws + 16778240);                  // ~21 MB
    unsigned short* mid   = (unsigned short*)(ws + 37749760);         // 8 MB (f16)
    unsigned short* Wt    = (unsigned short*)(ws + 46138368);         // 416 KB
    float*          biasD = (float*)(ws + 46564352);                  // 1.25 KB

    prep_all<<<dim3(2101), dim3(256), 0, stream>>>(x, xb, v_w, qd_w, qs_w, qw_w,
                                                   out_w, qd_b, qw_b, Wt, biasD, vpad);

    gemm_proj<<<dim3(256, 9), dim3(256), 0, stream>>>(xb, Wt, v_b, biasD, v_bf, proj);

    dcn_sample7<<<dim3(NPIX / 8), dim3(256), 0, stream>>>(v_bf, proj, prior, dscale, mid);

    gemm_out<<<dim3(256, 4), dim3(256), 0, stream>>>(mid, Wt + 576 * 256, out_b, out);
}

// Round 14
// 56.180 us; speedup vs baseline: 7.2766x; 1.0052x over previous
//
#include <hip/hip_runtime.h>
#include <hip/hip_fp16.h>

#define NPIX 16384

typedef __attribute__((ext_vector_type(8))) short short8;
typedef __attribute__((ext_vector_type(8))) _Float16 half8;
typedef __attribute__((ext_vector_type(4))) float f32x4;

__device__ __forceinline__ unsigned short f2bf(float f) {
    unsigned u = __float_as_uint(f);
    unsigned r = (u + 0x7fffu + ((u >> 16) & 1u)) >> 16;
    return (unsigned short)r;
}
__device__ __forceinline__ unsigned short f2h_us(float f) {
    union { _Float16 h; unsigned short u; } cv;
    cv.h = (_Float16)f;
    return cv.u;
}
__device__ __forceinline__ unsigned hdup(float f) {
    unsigned short u = f2h_us(f);
    return (unsigned)u | ((unsigned)u << 16);
}
__device__ __forceinline__ unsigned hfma2u(unsigned w, unsigned v, unsigned a) {
    union { unsigned u; __half2 h; } W, V, A, R;
    W.u = w; V.u = v; A.u = a;
    R.h = __hfma2(W.h, V.h, A.h);
    return R.u;
}
__device__ __forceinline__ unsigned hadd2u(unsigned a, unsigned b) {
    union { unsigned u; __half2 h; } A, B, R;
    A.u = a; B.u = b;
    R.h = __hadd2(A.h, B.h);
    return R.u;
}

#define GLOAD16(SRC, DST) \
    __builtin_amdgcn_global_load_lds( \
        (const __attribute__((address_space(1))) unsigned*)(SRC), \
        (__attribute__((address_space(3))) unsigned*)(DST), 16, 0, 0)

// ---------------------------------------------------------------------------
// prep_all: blocks 0..2047 x->bf16 (XCD-aligned); 2048..2099 Wt transpose;
// 2100 biasD+pad. Wt n-rows: 0-255 v_w | 256-399 qd_w | 400-471 qs_w |
// 472-543 qw_w | 544-575 zero | 576-831 out_w (f16; rest bf16).
// ---------------------------------------------------------------------------
__device__ __forceinline__ float wsrc(int k, int n,
    const float* v_w, const float* qd_w, const float* qs_w,
    const float* qw_w, const float* out_w)
{
    if (n < 256) return v_w[k * 256 + n];
    n -= 256;
    if (n < 144) return qd_w[k * 144 + n];
    n -= 144;
    if (n < 72)  return qs_w[k * 72 + n];
    n -= 72;
    if (n < 72)  return qw_w[k * 72 + n];
    n -= 72;
    if (n < 32)  return 0.f;
    return out_w[k * 256 + (n - 32)];
}

__global__ __launch_bounds__(256) void prep_all(
    const float* __restrict__ x, unsigned short* __restrict__ xb,
    const float* __restrict__ v_w, const float* __restrict__ qd_w,
    const float* __restrict__ qs_w, const float* __restrict__ qw_w,
    const float* __restrict__ out_w, const float* __restrict__ qd_b,
    const float* __restrict__ qw_b,
    unsigned short* __restrict__ Wt, float* __restrict__ biasD,
    unsigned short* __restrict__ vpad)
{
    __shared__ float t[64][65];
    const int bid = blockIdx.x;
    const int tid = threadIdx.x;

    if (bid < 2048) {
        const int bb = (bid >> 3) + (bid & 7) * 256;
        const size_t i = (size_t)bb * 256 + tid;
        const float4 v0 = *(const float4*)(x + i * 8);
        const float4 v1 = *(const float4*)(x + i * 8 + 4);
        uint4 pk;
        pk.x = f2bf(v0.x) | ((unsigned)f2bf(v0.y) << 16);
        pk.y = f2bf(v0.z) | ((unsigned)f2bf(v0.w) << 16);
        pk.z = f2bf(v1.x) | ((unsigned)f2bf(v1.y) << 16);
        pk.w = f2bf(v1.z) | ((unsigned)f2bf(v1.w) << 16);
        *(uint4*)(xb + i * 8) = pk;
        return;
    }
    if (bid == 2100) {
        for (int i = tid; i < 320; i += 256) {
            float bv = 0.f;
            if (i < 144)                  bv = qd_b[i];
            else if (i >= 216 && i < 288) bv = qw_b[i - 216];
            biasD[i] = bv;
        }
        for (int i = tid; i < 512; i += 256) vpad[i] = 0;
        return;
    }
    const int tile = bid - 2048;
    const int tn = tile % 13;
    const int tk = tile / 13;
    #pragma unroll
    for (int i = 0; i < 16; ++i) {
        const int idx = tid + i * 256;
        const int r = idx >> 6;
        const int c = idx & 63;
        t[r][c] = wsrc(tk * 64 + r, tn * 64 + c, v_w, qd_w, qs_w, qw_w, out_w);
    }
    __syncthreads();
    const bool asF16 = (tn >= 9);
    #pragma unroll
    for (int i = 0; i < 8; ++i) {
        const int idx = tid + i * 256;
        const int rn = idx >> 5;
        const int cc = idx & 31;
        unsigned pk;
        if (asF16)
            pk = (unsigned)f2h_us(t[cc * 2][rn]) | ((unsigned)f2h_us(t[cc * 2 + 1][rn]) << 16);
        else
            pk = (unsigned)f2bf(t[cc * 2][rn]) | ((unsigned)f2bf(t[cc * 2 + 1][rn]) << 16);
        ((unsigned*)(Wt + (size_t)(tn * 64 + rn) * 256 + tk * 64))[cc] = pk;
    }
}

// ---------------------------------------------------------------------------
// gemm_proj: [NPIX][256]bf16 @ Wt[j*64..][256]^T, j=0..8. XCD-remapped rows.
//   j<4  -> v_bf F16 GROUP-MAJOR [b][g][4096][32];  j>=4 -> proj f32 [NPIX][320]
// ---------------------------------------------------------------------------
__global__ __launch_bounds__(256) void gemm_proj(
    const unsigned short* __restrict__ A, const unsigned short* __restrict__ Wt,
    const float* __restrict__ v_b, const float* __restrict__ biasD,
    unsigned short* __restrict__ v_bf, float* __restrict__ proj)
{
    __shared__ unsigned short As[64 * 256];
    __shared__ unsigned short Bs[64 * 256];

    const int tid  = threadIdx.x;
    const int wid  = tid >> 6;
    const int lane = tid & 63;
    const int bx   = blockIdx.x;
    const int tile = (bx >> 3) + (bx & 7) * 32;
    const int row0 = tile * 64;
    const int j    = blockIdx.y;

    const unsigned short* Ab = A  + (size_t)row0 * 256;
    const unsigned short* Bb = Wt + (size_t)(j * 64) * 256;
    const int rl = lane >> 5;
    const int gl = lane & 31;

    #pragma unroll
    for (int it = 0; it < 8; ++it) {
        const int r   = wid * 16 + it * 2 + rl;
        const int gsw = gl ^ (r & 7);
        GLOAD16(Ab + r * 256 + gsw * 8, &As[(wid * 16 + it * 2) * 256]);
        GLOAD16(Bb + r * 256 + gsw * 8, &Bs[(wid * 16 + it * 2) * 256]);
    }
    asm volatile("s_waitcnt vmcnt(0)" ::: "memory");
    __syncthreads();

    f32x4 acc00 = {0,0,0,0}, acc01 = {0,0,0,0};
    f32x4 acc10 = {0,0,0,0}, acc11 = {0,0,0,0};

    const int wr = (wid >> 1) * 32;
    const int wc = (wid & 1) * 32;
    const int fr = lane & 15;
    const int fg = lane >> 4;

    const int ra0 = wr + fr, ra1 = ra0 + 16;
    const int rb0 = wc + fr, rb1 = rb0 + 16;
    const int sa  = ra0 & 7;
    const int sb  = rb0 & 7;

    #pragma unroll
    for (int t = 0; t < 8; ++t) {
        const int gran = t * 4 + fg;
        short8 a0 = *(const short8*)&As[ra0 * 256 + (gran ^ sa) * 8];
        short8 a1 = *(const short8*)&As[ra1 * 256 + (gran ^ sa) * 8];
        short8 b0 = *(const short8*)&Bs[rb0 * 256 + (gran ^ sb) * 8];
        short8 b1 = *(const short8*)&Bs[rb1 * 256 + (gran ^ sb) * 8];
        acc00 = __builtin_amdgcn_mfma_f32_16x16x32_bf16(a0, b0, acc00, 0, 0, 0);
        acc01 = __builtin_amdgcn_mfma_f32_16x16x32_bf16(a0, b1, acc01, 0, 0, 0);
        acc10 = __builtin_amdgcn_mfma_f32_16x16x32_bf16(a1, b0, acc10, 0, 0, 0);
        acc11 = __builtin_amdgcn_mfma_f32_16x16x32_bf16(a1, b1, acc11, 0, 0, 0);
    }

    if (j < 4) {
        const int colA = j * 64 + wc + fr;
        const int colB = colA + 16;
        const int gA = colA >> 5, cA = colA & 31;
        const int gB = colB >> 5, cB = colB & 31;
        const float biasA = v_b[colA];
        const float biasB = v_b[colB];
        #pragma unroll
        for (int jj = 0; jj < 4; ++jj) {
            const int r0a = row0 + wr + fg * 4 + jj;
            const int r1a = r0a + 16;
            const int b0i = r0a >> 12;
            const int hw0 = r0a & 4095, hw1 = r1a & 4095;
            v_bf[((size_t)(b0i * 8 + gA) * 4096 + hw0) * 32 + cA] = f2h_us(acc00[jj] + biasA);
            v_bf[((size_t)(b0i * 8 + gB) * 4096 + hw0) * 32 + cB] = f2h_us(acc01[jj] + biasB);
            v_bf[((size_t)(b0i * 8 + gA) * 4096 + hw1) * 32 + cA] = f2h_us(acc10[jj] + biasA);
            v_bf[((size_t)(b0i * 8 + gB) * 4096 + hw1) * 32 + cB] = f2h_us(acc11[jj] + biasB);
        }
    } else {
        const int colA = (j - 4) * 64 + wc + fr;
        const int colB = colA + 16;
        const float biasA = biasD[colA];
        const float biasB = biasD[colB];
        #pragma unroll
        for (int jj = 0; jj < 4; ++jj) {
            const int r0a = row0 + wr + fg * 4 + jj;
            const int r1a = r0a + 16;
            proj[(size_t)r0a * 320 + colA] = acc00[jj] + biasA;
            proj[(size_t)r0a * 320 + colB] = acc01[jj] + biasB;
            proj[(size_t)r1a * 320 + colA] = acc10[jj] + biasA;
            proj[(size_t)r1a * 320 + colB] = acc11[jj] + biasB;
        }
    }
}

// ---------------------------------------------------------------------------
// gemm_out: out[M][256] = mid[M][256](f16) @ WtO(f16)^T + out_b (f32 out).
// ---------------------------------------------------------------------------
__global__ __launch_bounds__(256) void gemm_out(
    const unsigned short* __restrict__ A, const unsigned short* __restrict__ WtO,
    const float* __restrict__ bias, float* __restrict__ Y)
{
    __shared__ unsigned short As[64 * 256];
    __shared__ unsigned short Bs[64 * 256];

    const int tid  = threadIdx.x;
    const int wid  = tid >> 6;
    const int lane = tid & 63;
    const int bx   = blockIdx.x;
    const int tile = (bx >> 3) + (bx & 7) * 32;
    const int row0 = tile * 64;
    const int col0 = blockIdx.y * 64;

    const unsigned short* Ab = A   + (size_t)row0 * 256;
    const unsigned short* Bb = WtO + (size_t)col0 * 256;
    const int rl = lane >> 5;
    const int gl = lane & 31;

    #pragma unroll
    for (int it = 0; it < 8; ++it) {
        const int r   = wid * 16 + it * 2 + rl;
        const int gsw = gl ^ (r & 7);
        GLOAD16(Ab + r * 256 + gsw * 8, &As[(wid * 16 + it * 2) * 256]);
        GLOAD16(Bb + r * 256 + gsw * 8, &Bs[(wid * 16 + it * 2) * 256]);
    }
    asm volatile("s_waitcnt vmcnt(0)" ::: "memory");
    __syncthreads();

    f32x4 acc00 = {0,0,0,0}, acc01 = {0,0,0,0};
    f32x4 acc10 = {0,0,0,0}, acc11 = {0,0,0,0};

    const int wr = (wid >> 1) * 32;
    const int wc = (wid & 1) * 32;
    const int fr = lane & 15;
    const int fg = lane >> 4;

    const int ra0 = wr + fr, ra1 = ra0 + 16;
    const int rb0 = wc + fr, rb1 = rb0 + 16;
    const int sa  = ra0 & 7;
    const int sb  = rb0 & 7;

    #pragma unroll
    for (int t = 0; t < 8; ++t) {
        const int gran = t * 4 + fg;
        half8 a0 = *(const half8*)&As[ra0 * 256 + (gran ^ sa) * 8];
        half8 a1 = *(const half8*)&As[ra1 * 256 + (gran ^ sa) * 8];
        half8 b0 = *(const half8*)&Bs[rb0 * 256 + (gran ^ sb) * 8];
        half8 b1 = *(const half8*)&Bs[rb1 * 256 + (gran ^ sb) * 8];
        acc00 = __builtin_amdgcn_mfma_f32_16x16x32_f16(a0, b0, acc00, 0, 0, 0);
        acc01 = __builtin_amdgcn_mfma_f32_16x16x32_f16(a0, b1, acc01, 0, 0, 0);
        acc10 = __builtin_amdgcn_mfma_f32_16x16x32_f16(a1, b0, acc10, 0, 0, 0);
        acc11 = __builtin_amdgcn_mfma_f32_16x16x32_f16(a1, b1, acc11, 0, 0, 0);
    }

    const int colA = col0 + wc + fr;
    const int colB = colA + 16;
    const float biasA = bias[colA];
    const float biasB = bias[colB];
    #pragma unroll
    for (int jj = 0; jj < 4; ++jj) {
        const int r0a = row0 + wr + fg * 4 + jj;
        const int r1a = r0a + 16;
        Y[(size_t)r0a * 256 + colA] = acc00[jj] + biasA;
        Y[(size_t)r0a * 256 + colB] = acc01[jj] + biasB;
        Y[(size_t)r1a * 256 + colA] = acc10[jj] + biasA;
        Y[(size_t)r1a * 256 + colB] = acc11[jj] + biasB;
    }
}

// ---------------------------------------------------------------------------
// Sampler v7: v6 minus the projs LDS staging (proj read direct from global,
// L2-resident). LDS = 13.8 KB -> wave-cap occupancy: 8 blocks/CU, entire
// 2048-block grid co-resident (256 CU x 8). Everything else identical to v6.
// ---------------------------------------------------------------------------
__global__ __launch_bounds__(256) void dcn_sample7(
    const unsigned short* __restrict__ vbuf,  // [4][8][4096][32] f16
    const float* __restrict__ proj,           // [NPIX][320]
    const float* __restrict__ prior,          // [K][2]
    const float* __restrict__ dscale,         // [G]
    unsigned short* __restrict__ mid)         // [NPIX][256] f16
{
    __shared__ int      offs[576 * 2];   //  4608 B
    __shared__ unsigned wpk [576 * 4];   //  9216 B

    const int tid = threadIdx.x;
    const int bid  = blockIdx.x;
    const int wg   = (bid & 7) * 256 + (bid >> 3);
    const int pix0 = wg * 8;

    for (int it = tid; it < 576; it += 256) {
        const int p   = it / 72;
        const int rem = it - p * 72;
        const int g   = rem / 9;
        const int k   = rem - g * 9;
        const int pix = pix0 + p;
        const int b   = pix >> 12;
        const int hw  = pix & 4095;
        const int h   = hw >> 6, w = hw & 63;

        const float* row = proj + (size_t)pix * 320;
        const float qdx = row[g * 18 + k * 2 + 0];
        const float qdy = row[g * 18 + k * 2 + 1];
        const float s   = row[144 + g * 9 + k] + dscale[g];
        const float wt  = row[216 + g * 9 + k];
        const float sig6 = 6.0f / (1.0f + __expf(-s));
        const float px = (float)w + (qdx + prior[k * 2 + 0]) * sig6;
        const float py = (float)h + (qdy + prior[k * 2 + 1]) * sig6;

        const float x0f = floorf(px), y0f = floorf(py);
        const int ix = (int)x0f, iy = (int)y0f;
        const float wx1 = px - x0f, wx0 = 1.f - wx1;
        const float wy1 = py - y0f, wy0 = 1.f - wy1;
        const int plane = (b * 8 + g) << 12;

        const bool vy0 = (iy >= 0) & (iy < 64);
        const bool vy1 = (iy >= -1) & (iy < 63);
        const bool vx0 = (ix >= 0) & (ix < 64);
        const bool vx1 = (ix >= -1) & (ix < 63);
        const float w00 = (vy0 & vx0) ? wt * wy0 * wx0 : 0.f;
        const float w10 = (vy1 & vx0) ? wt * wy1 * wx0 : 0.f;
        const float w01 = (vy0 & vx1) ? wt * wy0 * wx1 : 0.f;
        const float w11 = (vy1 & vx1) ? wt * wy1 * wx1 : 0.f;
        wpk[it * 4 + 0] = hdup(w00);
        wpk[it * 4 + 1] = hdup(w10);
        wpk[it * 4 + 2] = hdup(w01);
        wpk[it * 4 + 3] = hdup(w11);

        const int xs  = min(max(ix,     -1), 63);
        const int y0c = min(max(iy,      0), 63);
        const int y1c = min(max(iy + 1,  0), 63);
        offs[it * 2 + 0] = (plane + y0c * 64 + xs) * 64;   // BYTE offsets
        offs[it * 2 + 1] = (plane + y1c * 64 + xs) * 64;
    }
    __syncthreads();

    const int p4 = tid >> 6;
    const int g  = (tid >> 3) & 7;
    const int q  = tid & 7;
    const int xh = q >> 2;
    const int qb = q * 16;
    const char* vbb = (const char*)vbuf;

    unsigned aA0=0,aA1=0,aA2=0,aA3=0, aB0=0,aB1=0,aB2=0,aB3=0;
    unsigned bA0=0,bA1=0,bA2=0,bA3=0, bB0=0,bB1=0,bB2=0,bB3=0;
    const int item0a = p4 * 72 + g * 9;
    const int item0b = (p4 + 4) * 72 + g * 9;

    #pragma unroll
    for (int k = 0; k < 9; ++k) {
        {
            const int it = item0a + k;
            const int2  o2 = *(const int2*)&offs[it * 2];
            const uint2 wp = *(const uint2*)&wpk[it * 4 + xh * 2];
            const uint4 r0 = *(const uint4*)(vbb + o2.x + qb);
            const uint4 r1 = *(const uint4*)(vbb + o2.y + qb);
            aA0 = hfma2u(wp.x, r0.x, aA0);
            aA1 = hfma2u(wp.x, r0.y, aA1);
            aA2 = hfma2u(wp.x, r0.z, aA2);
            aA3 = hfma2u(wp.x, r0.w, aA3);
            aB0 = hfma2u(wp.y, r1.x, aB0);
            aB1 = hfma2u(wp.y, r1.y, aB1);
            aB2 = hfma2u(wp.y, r1.z, aB2);
            aB3 = hfma2u(wp.y, r1.w, aB3);
        }
        {
            const int it = item0b + k;
            const int2  o2 = *(const int2*)&offs[it * 2];
            const uint2 wp = *(const uint2*)&wpk[it * 4 + xh * 2];
            const uint4 r0 = *(const uint4*)(vbb + o2.x + qb);
            const uint4 r1 = *(const uint4*)(vbb + o2.y + qb);
            bA0 = hfma2u(wp.x, r0.x, bA0);
            bA1 = hfma2u(wp.x, r0.y, bA1);
            bA2 = hfma2u(wp.x, r0.z, bA2);
            bA3 = hfma2u(wp.x, r0.w, bA3);
            bB0 = hfma2u(wp.y, r1.x, bB0);
            bB1 = hfma2u(wp.y, r1.y, bB1);
            bB2 = hfma2u(wp.y, r1.z, bB2);
            bB3 = hfma2u(wp.y, r1.w, bB3);
        }
    }

    uint4 oA, oB;
    {
        unsigned c;
        c = hadd2u(aA0, aB0); c = hadd2u(c, (unsigned)__shfl_xor((int)c, 4)); oA.x = c;
        c = hadd2u(aA1, aB1); c = hadd2u(c, (unsigned)__shfl_xor((int)c, 4)); oA.y = c;
        c = hadd2u(aA2, aB2); c = hadd2u(c, (unsigned)__shfl_xor((int)c, 4)); oA.z = c;
        c = hadd2u(aA3, aB3); c = hadd2u(c, (unsigned)__shfl_xor((int)c, 4)); oA.w = c;
        c = hadd2u(bA0, bB0); c = hadd2u(c, (unsigned)__shfl_xor((int)c, 4)); oB.x = c;
        c = hadd2u(bA1, bB1); c = hadd2u(c, (unsigned)__shfl_xor((int)c, 4)); oB.y = c;
        c = hadd2u(bA2, bB2); c = hadd2u(c, (unsigned)__shfl_xor((int)c, 4)); oB.z = c;
        c = hadd2u(bA3, bB3); c = hadd2u(c, (unsigned)__shfl_xor((int)c, 4)); oB.w = c;
    }
    if (xh == 0) {
        const int cq8 = (q & 3) * 8;
        *(uint4*)(mid + (size_t)(pix0 + p4) * 256 + g * 32 + cq8) = oA;
        *(uint4*)(mid + (size_t)(pix0 + p4 + 4) * 256 + g * 32 + cq8) = oB;
    }
}

// ---------------------------------------------------------------------------
extern "C" void kernel_launch(void* const* d_in, const int* in_sizes, int n_in,
                              void* d_out, int out_size, void* d_ws, size_t ws_size,
                              hipStream_t stream)
{
    (void)in_sizes; (void)n_in; (void)out_size; (void)ws_size;

    const float* x      = (const float*)d_in[0];
    const float* v_w    = (const float*)d_in[1];
    const float* v_b    = (const float*)d_in[2];
    const float* qd_w   = (const float*)d_in[3];
    const float* qd_b   = (const float*)d_in[4];
    const float* qs_w   = (const float*)d_in[5];
    const float* qw_w   = (const float*)d_in[6];
    const float* qw_b   = (const float*)d_in[7];
    const float* out_w  = (const float*)d_in[8];
    const float* out_b  = (const float*)d_in[9];
    const float* prior  = (const float*)d_in[10];
    const float* dscale = (const float*)d_in[11];
    float* out = (float*)d_out;

    char* ws = (char*)d_ws;
    unsigned short* xb    = (unsigned short*)(ws);                    // 8 MB
    unsigned short* v_bf  = (unsigned short*)(ws + 8388608);          // 8 MB (f16)
    unsigned short* vpad  = (unsigned short*)(ws + 16777216);         // 1 KB guard
    float*          proj  = (float*)(ws + 16778240);                  // ~21 MB
    unsigned short* mid   = (unsigned short*)(ws + 37749760);         // 8 MB (f16)
    unsigned short* Wt    = (unsigned short*)(ws + 46138368);         // 416 KB
    float*          biasD = (float*)(ws + 46564352);                  // 1.25 KB

    prep_all<<<dim3(2101), dim3(256), 0, stream>>>(x, xb, v_w, qd_w, qs_w, qw_w,
                                                   out_w, qd_b, qw_b, Wt, biasD, vpad);

    gemm_proj<<<dim3(256, 9), dim3(256), 0, stream>>>(xb, Wt, v_b, biasD, v_bf, proj);

    dcn_sample7<<<dim3(NPIX / 8), dim3(256), 0, stream>>>(v_bf, proj, prior, dscale, mid);

    gemm_out<<<dim3(256, 4), dim3(256), 0, stream>>>(mid, Wt + 576 * 256, out_b, out);
}